// Round 2
// baseline (7135.929 us; speedup 1.0000x reference)
//
#include <hip/hip_runtime.h>
#include <math.h>

// ---------------------------------------------------------------------------
// Faster-RCNN head, fp64 through the rois-determining path (FPN convs, RPN,
// decode, top-k, NMS, roi-align sampling); fp32 FC head.
//
// Workspace layout (BYTES), total 195,944,064 (~187 MB):
//   o64  (double, 11,173,888 el)   [0          .. 89,391,104)
//   p64  (double, 11,173,888 el)   [89,391,104 .. 178,782,208)
//   c6   (float,     262,144 el)   [178,782,208 .. 179,830,784)
//   scores (double,  392,832 el)   [179,830,784 .. 182,973,440)
//   boxes  (double,1,571,328 el)   [182,973,440 .. 195,544,064)
//   ss (double 2000)               [195,544,064 .. 195,560,064)
//   sb (double 8000)               [195,560,064 .. 195,624,064)
//   rois64 (double 8000)           [195,624,064 .. 195,688,064)
//   supp (u64 32000)               [195,688,064 .. 195,944,064)
//   feats (float 25,088,000) OVERLAPS p64+c6+scores+boxes (dead then):
//                                  [89,391,104 .. 189,743,104)
//   fc1/fc2 (float 2,048,000 ea) OVERLAP o64 (dead after roi_align):
//                                  [0 .. 8,192,000) / [8,192,000 .. 16,384,000)
// ---------------------------------------------------------------------------

#define NUM_ANCH 196416

// ---------------- maxpool2 c5 (2,16,16,2048) -> c6 (2,8,8,2048), f32 --------
__global__ void maxpool_kernel(const float* __restrict__ in, float* __restrict__ out) {
  int idx = blockIdx.x * 256 + threadIdx.x;     // 262144 total
  int c = idx & 2047;
  int x = (idx >> 11) & 7;
  int y = (idx >> 14) & 7;
  int b = idx >> 17;
  const float* p = in + (((size_t)b * 16 + 2 * y) * 16 + 2 * x) * 2048 + c;
  float m = fmaxf(fmaxf(p[0], p[2048]), fmaxf(p[16 * 2048], p[16 * 2048 + 2048]));
  out[idx] = m;
}

// ---------------- 1x1 lateral conv + bias, f32 in -> f64 out ----------------
// 4 pixels per block; x reads are block-uniform (scalar loads + broadcast).
template <int CIN>
__global__ __launch_bounds__(256) void lateral_d(
    const float* __restrict__ in, const float* __restrict__ w,
    const float* __restrict__ bias, double* __restrict__ out) {
  const int t = threadIdx.x;
  const size_t pix0 = (size_t)blockIdx.x * 4;
  double b = (double)bias[t];
  double a0 = b, a1 = b, a2 = b, a3 = b;
  const float* i0 = in + pix0 * CIN;
  for (int ci = 0; ci < CIN; ++ci) {
    double wv = (double)w[ci * 256 + t];
    a0 += (double)i0[ci] * wv;
    a1 += (double)i0[CIN + ci] * wv;
    a2 += (double)i0[2 * CIN + ci] * wv;
    a3 += (double)i0[3 * CIN + ci] * wv;
  }
  out[(pix0 + 0) * 256 + t] = a0;
  out[(pix0 + 1) * 256 + t] = a1;
  out[(pix0 + 2) * 256 + t] = a2;
  out[(pix0 + 3) * 256 + t] = a3;
}

// ---------------- fine += upsample2(coarse), C=256, f64 ---------------------
__global__ void upadd_d(double* __restrict__ fine, const double* __restrict__ coarse,
                        int Hf, int Wf) {
  int idx = blockIdx.x * 256 + threadIdx.x;
  int c = idx & 255;
  int rem = idx >> 8;
  int x = rem % Wf; rem /= Wf;
  int y = rem % Hf;
  int b = rem / Hf;
  fine[idx] += coarse[(((size_t)b * (Hf >> 1) + (y >> 1)) * (Wf >> 1) + (x >> 1)) * 256 + c];
}

// ---------------- 3x3 SAME conv 256->256 + bias (+relu), f64 ----------------
// 256 threads = one output channel each; 4 consecutive x per block.
template <bool RELU>
__global__ __launch_bounds__(256) void conv3x3_d(
    const double* __restrict__ in, const float* __restrict__ w,
    const float* __restrict__ bias, double* __restrict__ out, int H, int W) {
  __shared__ double sh[18 * 256];   // 36 KB: 3 rows x 6 cols x 256 ch
  const int t = threadIdx.x;
  const int x0 = blockIdx.x * 4;
  const int y = blockIdx.y;
  const int b = blockIdx.z;
#pragma unroll
  for (int v = 0; v < 18; ++v) {
    int row = v / 6, col = v % 6;
    int gy = y + row - 1, gx = x0 + col - 1;
    double val = 0.0;
    if (gy >= 0 && gy < H && gx >= 0 && gx < W)
      val = in[(((size_t)b * H + gy) * W + gx) * 256 + t];
    sh[v * 256 + t] = val;
  }
  __syncthreads();
  double acc0, acc1, acc2, acc3;
  acc0 = acc1 = acc2 = acc3 = (double)bias[t];
  for (int ky = 0; ky < 3; ++ky) {
    const double* srow = sh + ky * 6 * 256;
    const float* wk = w + (size_t)(ky * 3) * 65536 + t;
    for (int ci = 0; ci < 256; ++ci) {
      double l0 = srow[0 * 256 + ci], l1 = srow[1 * 256 + ci], l2 = srow[2 * 256 + ci];
      double l3 = srow[3 * 256 + ci], l4 = srow[4 * 256 + ci], l5 = srow[5 * 256 + ci];
      double w0 = (double)wk[ci * 256];
      double w1 = (double)wk[65536 + ci * 256];
      double w2 = (double)wk[131072 + ci * 256];
      acc0 += w0 * l0 + w1 * l1 + w2 * l2;
      acc1 += w0 * l1 + w1 * l2 + w2 * l3;
      acc2 += w0 * l2 + w1 * l3 + w2 * l4;
      acc3 += w0 * l3 + w1 * l4 + w2 * l5;
    }
  }
  if (RELU) {
    acc0 = fmax(acc0, 0.0); acc1 = fmax(acc1, 0.0);
    acc2 = fmax(acc2, 0.0); acc3 = fmax(acc3, 0.0);
  }
  double* op = out + (((size_t)b * H + y) * W + x0) * 256 + t;
  op[0] = acc0; op[256] = acc1; op[512] = acc2; op[768] = acc3;
}

// ---------------- RPN head (obj + delta 1x1) + anchor decode, f64 -----------
struct AnchorHW { double hh[9]; double ww[9]; };

__global__ __launch_bounds__(64) void rpn_head_d(
    const double* __restrict__ tmap,
    const float* __restrict__ w_obj, const float* __restrict__ b_obj,
    const float* __restrict__ w_dlt, const float* __restrict__ b_dlt,
    double* __restrict__ scores, double* __restrict__ boxes,
    int H, int W, int a_off, double stride, AnchorHW anc) {
  __shared__ double tv[256];
  __shared__ double dlt[36];
  const int t = threadIdx.x;
  const int x = blockIdx.x, y = blockIdx.y, b = blockIdx.z;
  const double* px = tmap + (((size_t)b * H + y) * W + x) * 256;
  tv[t] = px[t]; tv[t + 64] = px[t + 64]; tv[t + 128] = px[t + 128]; tv[t + 192] = px[t + 192];
  __syncthreads();
  double sacc = 0.0;
  if (t < 9) {
    sacc = (double)b_obj[t];
    for (int ci = 0; ci < 256; ++ci) sacc += tv[ci] * (double)w_obj[ci * 9 + t];
  } else if (t < 45) {
    int j = t - 9;
    double a = (double)b_dlt[j];
    for (int ci = 0; ci < 256; ++ci) a += tv[ci] * (double)w_dlt[ci * 36 + j];
    dlt[j] = a;
  }
  __syncthreads();
  if (t < 9) {
    int ai = a_off + (y * W + x) * 9 + t;
    scores[(size_t)b * NUM_ANCH + ai] = sacc;
    // anchors: f64 arithmetic, clipped, then cast f32 (make_anchors does
    // np-f64 -> jnp.float32); decode's ahw/act are f32 ops, rest promotes f64.
    double cy = (y + 0.5) * stride, cx = (x + 0.5) * stride;
    double hh = anc.hh[t], ww = anc.ww[t];
    float ay1 = (float)fmin(fmax(cy - hh * 0.5, 0.0), 512.0);
    float ax1 = (float)fmin(fmax(cx - ww * 0.5, 0.0), 512.0);
    float ay2 = (float)fmin(fmax(cy + hh * 0.5, 0.0), 512.0);
    float ax2 = (float)fmin(fmax(cx + ww * 0.5, 0.0), 512.0);
    float ahf = ay2 - ay1, awf = ax2 - ax1;
    float actyf = ay1 + ahf * 0.5f, actxf = ax1 + awf * 0.5f;
    double dy = dlt[t * 4 + 0], dx = dlt[t * 4 + 1];
    double dh = dlt[t * 4 + 2], dw = dlt[t * 4 + 3];
    double ncy = dy * (double)ahf + (double)actyf;
    double ncx = dx * (double)awf + (double)actxf;
    double nh = exp(dh) * (double)ahf;
    double nw = exp(dw) * (double)awf;
    double* bo = boxes + ((size_t)b * NUM_ANCH + ai) * 4;
    bo[0] = ncy - nh * 0.5;
    bo[1] = ncx - nw * 0.5;
    bo[2] = ncy + nh * 0.5;
    bo[3] = ncx + nw * 0.5;
  }
}

// ---------------- exact top-1000 per batch (f64 radix-select + bitonic) -----
__device__ inline unsigned long long dkey(double f) {
  unsigned long long u = (unsigned long long)__double_as_longlong(f);
  return u ^ ((unsigned long long)((long long)u >> 63) | 0x8000000000000000ull);
}

__global__ __launch_bounds__(1024) void topk_d(
    const double* __restrict__ scores, const double* __restrict__ boxes,
    double* __restrict__ ss, double* __restrict__ sb) {
  const int A = NUM_ANCH;
  __shared__ unsigned hist[256];
  __shared__ unsigned long long kk[2048];
  __shared__ unsigned id[2048];
  __shared__ unsigned long long s_prefix;
  __shared__ unsigned s_need, s_cnt;
  const int b = blockIdx.x, t = threadIdx.x;
  const double* sc = scores + (size_t)b * A;
  if (t == 0) { s_prefix = 0ull; s_need = 1000; s_cnt = 0; }
  __syncthreads();
  for (int r = 0; r < 8; ++r) {
    if (t < 256) hist[t] = 0;
    __syncthreads();
    const int shift = 56 - 8 * r;
    const unsigned long long prefix = s_prefix;
    unsigned long long maskHigh = 0ull;
    if (r != 0) maskHigh = (~0ull) << (shift + 8);
    for (int i = t; i < A; i += 1024) {
      unsigned long long k = dkey(sc[i]);
      if ((k & maskHigh) == prefix) atomicAdd(&hist[(unsigned)(k >> shift) & 255u], 1u);
    }
    __syncthreads();
    if (t == 0) {
      unsigned need = s_need, cum = 0;
      for (int bin = 255; bin >= 0; --bin) {
        cum += hist[bin];
        if (cum >= need) {
          s_prefix = prefix | ((unsigned long long)bin << shift);
          s_need = need - (cum - hist[bin]);
          break;
        }
      }
    }
    __syncthreads();
  }
  const unsigned long long K = s_prefix;  // exact key of 1000th-largest score
  for (int i = t; i < A; i += 1024) {
    unsigned long long k = dkey(sc[i]);
    if (k >= K) {
      unsigned pos = atomicAdd(&s_cnt, 1u);
      if (pos < 2048) { kk[pos] = k; id[pos] = (unsigned)i; }
    }
  }
  __syncthreads();
  unsigned cnt = s_cnt;
  for (int i = t; i < 2048; i += 1024)
    if (i >= cnt) { kk[i] = 0ull; id[i] = 0xFFFFFFFFu; }
  __syncthreads();
  // bitonic, descending by key, ties by index ascending
  for (int k = 2; k <= 2048; k <<= 1) {
    for (int j = k >> 1; j > 0; j >>= 1) {
#pragma unroll
      for (int u = 0; u < 2; ++u) {
        int i = t + u * 1024;
        int ixj = i ^ j;
        if (ixj > i) {
          unsigned long long ka = kk[i], kc = kk[ixj];
          unsigned ia = id[i], ic = id[ixj];
          bool cPrec = (kc > ka) || (kc == ka && ic < ia);
          bool up = (i & k) != 0;
          if (cPrec != up) { kk[i] = kc; kk[ixj] = ka; id[i] = ic; id[ixj] = ia; }
        }
      }
      __syncthreads();
    }
  }
  if (t < 1000) {
    unsigned idx = id[t];
    ss[b * 1000 + t] = sc[idx];
    const double* bp = boxes + ((size_t)b * A + idx) * 4;
    double* op = sb + (b * 1000 + t) * 4;
    op[0] = bp[0]; op[1] = bp[1]; op[2] = bp[2]; op[3] = bp[3];
  }
}

// ---------------- suppression bit-matrix (iou>0.7 & j>i), f64 ---------------
__global__ void suppmat_d(const double* __restrict__ sb,
                          unsigned long long* __restrict__ supp) {
  int g = blockIdx.x * 256 + threadIdx.x;   // 32000 = 2*1000*16
  int w = g & 15;
  int i = (g >> 4) % 1000;
  int b = g / 16000;
  const double* bx = sb + b * 4000;
  double y1 = bx[i * 4 + 0], x1 = bx[i * 4 + 1], y2 = bx[i * 4 + 2], x2 = bx[i * 4 + 3];
  double ai = (y2 - y1) * (x2 - x1);
  unsigned long long m = 0;
  for (int q = 0; q < 64; ++q) {
    int j = w * 64 + q;
    if (j > i && j < 1000) {
      double by1 = bx[j * 4 + 0], bx1 = bx[j * 4 + 1], by2 = bx[j * 4 + 2], bx2 = bx[j * 4 + 3];
      double aj = (by2 - by1) * (bx2 - bx1);
      double iy1 = fmax(y1, by1), ix1 = fmax(x1, bx1);
      double iy2 = fmin(y2, by2), ix2 = fmin(x2, bx2);
      double inter = fmax(iy2 - iy1, 0.0) * fmax(ix2 - ix1, 0.0);
      double iou = inter / (ai + aj - inter + 1e-8);
      if (iou > 0.7) m |= (1ull << q);
    }
  }
  supp[g] = m;
}

// ---------------- greedy NMS reduce + slot scatter --------------------------
__global__ __launch_bounds__(64) void nms_reduce_d(
    const double* __restrict__ ss, const double* __restrict__ sb,
    const unsigned long long* __restrict__ supp,
    float* __restrict__ rois, double* __restrict__ rois64) {
  __shared__ unsigned long long aliveS[16];
  __shared__ int pref[16];
  const int b = blockIdx.x, lane = threadIdx.x;
  unsigned long long myword = 0;
  if (lane < 16) {
    for (int q = 0; q < 64; ++q) {
      int j = lane * 64 + q;
      if (j < 1000 && ss[b * 1000 + j] > 0.0) myword |= (1ull << q);
    }
  }
  for (int i = 0; i < 1000; ++i) {
    unsigned long long wv = __shfl(myword, i >> 6);
    if ((wv >> (i & 63)) & 1ull) {
      if (lane < 16) myword &= ~supp[(size_t)b * 16000 + i * 16 + lane];
    }
  }
  if (lane < 16) aliveS[lane] = myword;
  __syncthreads();
  if (lane == 0) {
    int s = 0;
    for (int w = 0; w < 16; ++w) { pref[w] = s; s += __popcll(aliveS[w]); }
  }
  float* ro = rois + b * 4000;
  double* rd = rois64 + b * 4000;
  for (int k = lane; k < 4000; k += 64) { ro[k] = 0.0f; rd[k] = 0.0; }
  __syncthreads();
  for (int j = lane; j < 1000; j += 64) {
    int w = j >> 6;
    unsigned long long word = aliveS[w];
    if ((word >> (j & 63)) & 1ull) {
      unsigned long long below = (j & 63) ? (word & ((1ull << (j & 63)) - 1ull)) : 0ull;
      int slot = pref[w] + __popcll(below);
      const double* bp = sb + (b * 1000 + j) * 4;
      ro[slot * 4 + 0] = (float)bp[0]; ro[slot * 4 + 1] = (float)bp[1];
      ro[slot * 4 + 2] = (float)bp[2]; ro[slot * 4 + 3] = (float)bp[3];
      rd[slot * 4 + 0] = bp[0]; rd[slot * 4 + 1] = bp[1];
      rd[slot * 4 + 2] = bp[2]; rd[slot * 4 + 3] = bp[3];
    }
  }
}

// ---------------- ROI align: f64 sampling of f64 maps -> f32 feats ----------
__global__ __launch_bounds__(256) void roi_align_d(
    const double* __restrict__ o2, const double* __restrict__ o3,
    const double* __restrict__ o4, const double* __restrict__ o5,
    const double* __restrict__ o6, const double* __restrict__ rois64,
    float* __restrict__ feats) {
  __shared__ double s_wy[14], s_wx[14];
  __shared__ int s_y0[14], s_y1[14], s_x0[14], s_x1[14];
  const int t = threadIdx.x;
  const int b = blockIdx.x / 1000, r = blockIdx.x % 1000;
  const double* box = rois64 + (b * 1000 + r) * 4;
  double b0 = box[0], b1 = box[1], b2 = box[2], b3 = box[3];
  double h = b2 - b0, w = b3 - b1;
  double size = sqrt(fmax(h * w, 1e-8));
  double lf = floor(log2(size / 224.0) + 4.0);
  lf = fmin(fmax(lf, 2.0), 6.0);
  int lvl = (int)lf;
  int stride_i = 1 << lvl;
  double stride = (double)stride_i;
  int fs_i = 512 >> lvl;
  double fs = (double)fs_i;
  if (t < 14) {
    double v = b0 / stride + ((t + 0.5) * (h / stride)) / 14.0 - 0.5;
    v = fmin(fmax(v, 0.0), fs - 1.0);
    int i0 = (int)floor(v);
    s_y0[t] = i0; s_y1[t] = min(i0 + 1, fs_i - 1); s_wy[t] = v - (double)i0;
  } else if (t >= 64 && t < 78) {
    int u = t - 64;
    double v = b1 / stride + ((u + 0.5) * (w / stride)) / 14.0 - 0.5;
    v = fmin(fmax(v, 0.0), fs - 1.0);
    int i0 = (int)floor(v);
    s_x0[u] = i0; s_x1[u] = min(i0 + 1, fs_i - 1); s_wx[u] = v - (double)i0;
  }
  __syncthreads();
  const double* omaps[5] = {o2, o3, o4, o5, o6};
  const double* fm = omaps[lvl - 2] + (size_t)b * fs_i * fs_i * 256 + t;
  float* op = feats + ((size_t)(b * 1000 + r) * 49) * 256 + t;
  for (int oy = 0; oy < 7; ++oy) {
    double acc[7] = {0, 0, 0, 0, 0, 0, 0};
#pragma unroll
    for (int sy = 0; sy < 2; ++sy) {
      int yy = oy * 2 + sy;
      int y0 = s_y0[yy], y1 = s_y1[yy];
      double wy = s_wy[yy];
      const double* r0 = fm + (size_t)y0 * fs_i * 256;
      const double* r1 = fm + (size_t)y1 * fs_i * 256;
      for (int ox = 0; ox < 7; ++ox) {
#pragma unroll
        for (int sx = 0; sx < 2; ++sx) {
          int xx = ox * 2 + sx;
          int x0 = s_x0[xx], x1 = s_x1[xx];
          double wx = s_wx[xx];
          double v00 = r0[x0 * 256], v01 = r0[x1 * 256];
          double v10 = r1[x0 * 256], v11 = r1[x1 * 256];
          double val = (1.0 - wy) * ((1.0 - wx) * v00 + wx * v01) +
                       wy * ((1.0 - wx) * v10 + wx * v11);
          acc[ox] += val;
        }
      }
    }
    for (int ox = 0; ox < 7; ++ox)
      op[(oy * 7 + ox) * 256] = (float)(acc[ox] * 0.25);
  }
}

// ---------------- fp32 tiled GEMM: C = relu?(A[MxK] @ B[KxN] + bias) --------
template <bool RELU>
__global__ __launch_bounds__(256) void gemm_kernel(
    const float* __restrict__ A, const float* __restrict__ Bw,
    const float* __restrict__ bias, float* __restrict__ C, int M, int N, int K) {
  __shared__ __align__(16) float As[16][64];
  __shared__ __align__(16) float Bs[16][64];
  const int t = threadIdx.x;
  const int tx = t & 15, ty = t >> 4;
  const int m0 = blockIdx.y * 64, n0 = blockIdx.x * 64;
  float acc[4][4] = {};
  for (int k0 = 0; k0 < K; k0 += 16) {
    {
      int m = t >> 2, k4 = (t & 3) * 4;
      float4 v = make_float4(0.f, 0.f, 0.f, 0.f);
      if (m0 + m < M) v = *(const float4*)&A[(size_t)(m0 + m) * K + k0 + k4];
      As[k4 + 0][m] = v.x; As[k4 + 1][m] = v.y; As[k4 + 2][m] = v.z; As[k4 + 3][m] = v.w;
    }
    {
      int k = t >> 4, n4 = (t & 15) * 4;
      float4 v = *(const float4*)&Bw[(size_t)(k0 + k) * N + n0 + n4];
      *(float4*)&Bs[k][n4] = v;
    }
    __syncthreads();
#pragma unroll
    for (int kk = 0; kk < 16; ++kk) {
      float4 av = *(const float4*)&As[kk][ty * 4];
      float4 bv = *(const float4*)&Bs[kk][tx * 4];
      float a[4] = {av.x, av.y, av.z, av.w};
      float bb[4] = {bv.x, bv.y, bv.z, bv.w};
#pragma unroll
      for (int i2 = 0; i2 < 4; ++i2)
#pragma unroll
        for (int j2 = 0; j2 < 4; ++j2) acc[i2][j2] += a[i2] * bb[j2];
    }
    __syncthreads();
  }
#pragma unroll
  for (int i2 = 0; i2 < 4; ++i2) {
    int m = m0 + ty * 4 + i2;
    if (m < M) {
      float4 v;
      float* vp = (float*)&v;
#pragma unroll
      for (int j2 = 0; j2 < 4; ++j2) {
        float val = acc[i2][j2] + bias[n0 + tx * 4 + j2];
        if (RELU) val = fmaxf(val, 0.0f);
        vp[j2] = val;
      }
      *(float4*)&C[(size_t)m * N + n0 + tx * 4] = v;
    }
  }
}

// ---------------- final box(4) + cls(81) heads, f32 -------------------------
__global__ __launch_bounds__(128) void boxcls_kernel(
    const float* __restrict__ x, const float* __restrict__ w_box,
    const float* __restrict__ b_box, const float* __restrict__ w_cls,
    const float* __restrict__ b_cls, float* __restrict__ out) {
  __shared__ float xv[1024];
  const int t = threadIdx.x;
  const int row = blockIdx.x;
  const float* xp = x + (size_t)row * 1024;
#pragma unroll
  for (int k = 0; k < 8; ++k) xv[k * 128 + t] = xp[k * 128 + t];
  __syncthreads();
  if (t < 4) {
    float acc = b_box[t];
    for (int k = 0; k < 1024; ++k) acc += xv[k] * w_box[k * 4 + t];
    out[8000 + row * 4 + t] = acc;
  } else if (t < 85) {
    int j = t - 4;
    float acc = b_cls[j];
    for (int k = 0; k < 1024; ++k) acc += xv[k] * w_cls[k * 81 + j];
    out[16000 + row * 81 + j] = acc;
  }
}

// ---------------------------------------------------------------------------
extern "C" void kernel_launch(void* const* d_in, const int* in_sizes, int n_in,
                              void* d_out, int out_size, void* d_ws, size_t ws_size,
                              hipStream_t stream) {
  (void)in_sizes; (void)n_in; (void)out_size; (void)ws_size;

  const float* c_in[4] = {(const float*)d_in[0], (const float*)d_in[1],
                          (const float*)d_in[2], (const float*)d_in[3]};
  const float *w_l[5], *b_l[5], *w_o[5], *b_o[5];
  for (int l = 0; l < 5; ++l) {
    w_l[l] = (const float*)d_in[4 + l * 4 + 0];
    b_l[l] = (const float*)d_in[4 + l * 4 + 1];
    w_o[l] = (const float*)d_in[4 + l * 4 + 2];
    b_o[l] = (const float*)d_in[4 + l * 4 + 3];
  }
  const float* w_rpn = (const float*)d_in[24];
  const float* b_rpn = (const float*)d_in[25];
  const float* w_obj = (const float*)d_in[26];
  const float* b_obj = (const float*)d_in[27];
  const float* w_dlt = (const float*)d_in[28];
  const float* b_dlt = (const float*)d_in[29];
  const float* w_fc1 = (const float*)d_in[30];
  const float* b_fc1 = (const float*)d_in[31];
  const float* w_fc2 = (const float*)d_in[32];
  const float* b_fc2 = (const float*)d_in[33];
  const float* w_box = (const float*)d_in[34];
  const float* b_box = (const float*)d_in[35];
  const float* w_cls = (const float*)d_in[36];
  const float* b_cls = (const float*)d_in[37];

  char* W8 = (char*)d_ws;
  double* o64 = (double*)(W8 + 0);
  double* p64 = (double*)(W8 + 89391104);
  float* c6buf = (float*)(W8 + 178782208);
  double* scores = (double*)(W8 + 179830784);
  double* boxes = (double*)(W8 + 182973440);
  double* ssb = (double*)(W8 + 195544064);
  double* sbb = (double*)(W8 + 195560064);
  double* rois64 = (double*)(W8 + 195624064);
  unsigned long long* suppb = (unsigned long long*)(W8 + 195688064);
  float* feats = (float*)(W8 + 89391104);   // overlaps dead p64/c6/scores/boxes
  float* fc1b = (float*)(W8 + 0);           // overlaps dead o64
  float* fc2b = (float*)(W8 + 8192000);
  float* outf = (float*)d_out;

  const size_t OFF[5] = {0, 8388608, 10485760, 11010048, 11141120};
  double* o[5]; double* p[5];
  for (int l = 0; l < 5; ++l) { o[l] = o64 + OFF[l]; p[l] = p64 + OFF[l]; }

  const int HS[5] = {128, 64, 32, 16, 8};
  const int a_off[5] = {0, 147456, 184320, 193536, 195840};
  const double strides[5] = {4.0, 8.0, 16.0, 32.0, 64.0};
  const double SZ[5] = {16.0, 32.0, 64.0, 128.0, 256.0};
  AnchorHW anc[5];
  for (int l = 0; l < 5; ++l) {
    const double ars[3] = {0.5, 1.0, 2.0};
    for (int s = 0; s < 3; ++s) {
      double sc = pow(2.0, s / 3.0);
      for (int a = 0; a < 3; ++a) {
        double sq = sqrt(ars[a]);
        anc[l].hh[s * 3 + a] = SZ[l] * sc / sq;
        anc[l].ww[s * 3 + a] = SZ[l] * sc * sq;
      }
    }
  }

  // ---- FPN (f64) ----
  maxpool_kernel<<<1024, 256, 0, stream>>>(c_in[3], c6buf);
  lateral_d<2048><<<32, 256, 0, stream>>>(c6buf, w_l[4], b_l[4], p[4]);      // p6
  lateral_d<2048><<<128, 256, 0, stream>>>(c_in[3], w_l[3], b_l[3], p[3]);   // p5
  upadd_d<<<512, 256, 0, stream>>>(p[3], p[4], 16, 16);
  lateral_d<1024><<<512, 256, 0, stream>>>(c_in[2], w_l[2], b_l[2], p[2]);   // p4
  upadd_d<<<2048, 256, 0, stream>>>(p[2], p[3], 32, 32);
  lateral_d<512><<<2048, 256, 0, stream>>>(c_in[1], w_l[1], b_l[1], p[1]);   // p3
  upadd_d<<<8192, 256, 0, stream>>>(p[1], p[2], 64, 64);
  lateral_d<256><<<8192, 256, 0, stream>>>(c_in[0], w_l[0], b_l[0], p[0]);   // p2
  upadd_d<<<32768, 256, 0, stream>>>(p[0], p[1], 128, 128);
  for (int l = 0; l < 5; ++l) {
    dim3 g(HS[l] / 4, HS[l], 2);
    conv3x3_d<false><<<g, 256, 0, stream>>>(p[l], w_o[l], b_o[l], o[l], HS[l], HS[l]);
  }
  // ---- RPN head (t-maps reuse p buffers) ----
  for (int l = 0; l < 5; ++l) {
    dim3 g(HS[l] / 4, HS[l], 2);
    conv3x3_d<true><<<g, 256, 0, stream>>>(o[l], w_rpn, b_rpn, p[l], HS[l], HS[l]);
  }
  for (int l = 0; l < 5; ++l) {
    dim3 g(HS[l], HS[l], 2);
    rpn_head_d<<<g, 64, 0, stream>>>(p[l], w_obj, b_obj, w_dlt, b_dlt, scores, boxes,
                                     HS[l], HS[l], a_off[l], strides[l], anc[l]);
  }
  // ---- top-1000 + NMS (f64) ----
  topk_d<<<2, 1024, 0, stream>>>(scores, boxes, ssb, sbb);
  suppmat_d<<<125, 256, 0, stream>>>(sbb, suppb);
  nms_reduce_d<<<2, 64, 0, stream>>>(ssb, sbb, suppb, outf, rois64);
  // ---- ROI align + FC head ----
  roi_align_d<<<2000, 256, 0, stream>>>(o[0], o[1], o[2], o[3], o[4], rois64, feats);
  gemm_kernel<true><<<dim3(16, 32), 256, 0, stream>>>(feats, w_fc1, b_fc1, fc1b, 2000, 1024, 12544);
  gemm_kernel<true><<<dim3(16, 32), 256, 0, stream>>>(fc1b, w_fc2, b_fc2, fc2b, 2000, 1024, 1024);
  boxcls_kernel<<<2000, 128, 0, stream>>>(fc2b, w_box, b_box, w_cls, b_cls, outf);
}

// Round 4
// 6127.399 us; speedup vs baseline: 1.1646x; 1.1646x over previous
//
#include <hip/hip_runtime.h>
#include <math.h>

// ---------------------------------------------------------------------------
// Faster-RCNN head, fp64 through the rois-determining path. Round 3:
//  - conv3x3 f64 MFMA with SELF-CALIBRATING D-layout: two probe mfmas
//    discover the (row,col) of each accumulator register slot at runtime,
//    so the kernel is correct under any D/C register permutation.
//  - fc GEMM 128x64/8x4 tile (from R2).
//
// Workspace layout (BYTES), total 195,944,064 (~187 MB):
//   o64  (double, 11,173,888 el)   [0          .. 89,391,104)
//   p64  (double, 11,173,888 el)   [89,391,104 .. 178,782,208)
//   c6   (float,     262,144 el)   [178,782,208 .. 179,830,784)
//   scores (double,  392,832 el)   [179,830,784 .. 182,973,440)
//   boxes  (double,1,571,328 el)   [182,973,440 .. 195,544,064)
//   ss/sb/rois64/supp tail         [195,544,064 .. 195,944,064)
//   feats (float) overlaps p64+..  [89,391,104 ..)
//   fc1/fc2 (float) overlap o64    [0 ..)
// ---------------------------------------------------------------------------

#define NUM_ANCH 196416

typedef double d4 __attribute__((ext_vector_type(4)));

// ---------------- maxpool2 c5 (2,16,16,2048) -> c6 (2,8,8,2048), f32 --------
__global__ void maxpool_kernel(const float* __restrict__ in, float* __restrict__ out) {
  int idx = blockIdx.x * 256 + threadIdx.x;     // 262144 total
  int c = idx & 2047;
  int x = (idx >> 11) & 7;
  int y = (idx >> 14) & 7;
  int b = idx >> 17;
  const float* p = in + (((size_t)b * 16 + 2 * y) * 16 + 2 * x) * 2048 + c;
  float m = fmaxf(fmaxf(p[0], p[2048]), fmaxf(p[16 * 2048], p[16 * 2048 + 2048]));
  out[idx] = m;
}

// ---------------- 1x1 lateral conv + bias, f32 in -> f64 out ----------------
template <int CIN>
__global__ __launch_bounds__(256) void lateral_d(
    const float* __restrict__ in, const float* __restrict__ w,
    const float* __restrict__ bias, double* __restrict__ out) {
  const int t = threadIdx.x;
  const size_t pix0 = (size_t)blockIdx.x * 4;
  double b = (double)bias[t];
  double a0 = b, a1 = b, a2 = b, a3 = b;
  const float* i0 = in + pix0 * CIN;
  for (int ci = 0; ci < CIN; ++ci) {
    double wv = (double)w[ci * 256 + t];
    a0 += (double)i0[ci] * wv;
    a1 += (double)i0[CIN + ci] * wv;
    a2 += (double)i0[2 * CIN + ci] * wv;
    a3 += (double)i0[3 * CIN + ci] * wv;
  }
  out[(pix0 + 0) * 256 + t] = a0;
  out[(pix0 + 1) * 256 + t] = a1;
  out[(pix0 + 2) * 256 + t] = a2;
  out[(pix0 + 3) * 256 + t] = a3;
}

// ---------------- fine += upsample2(coarse), C=256, f64 ---------------------
__global__ void upadd_d(double* __restrict__ fine, const double* __restrict__ coarse,
                        int Hf, int Wf) {
  int idx = blockIdx.x * 256 + threadIdx.x;
  int c = idx & 255;
  int rem = idx >> 8;
  int x = rem % Wf; rem /= Wf;
  int y = rem % Hf;
  int b = rem / Hf;
  fine[idx] += coarse[(((size_t)b * (Hf >> 1) + (y >> 1)) * (Wf >> 1) + (x >> 1)) * 256 + c];
}

// ---------------- 3x3 SAME conv 256->256 + bias (+relu), f64 MFMA -----------
// Block: 16 pixels (one row) x 256 cout. 4 waves; wave w owns cout [64w,64w+64)
// as 4 mfma 16x16 tiles. K = ky(3) x kx(3) x ci(256) via mfma_f64_16x16x4.
// A/B operand layout (CDNA docs): A[i][k] in lane i+16k; B[k][j] in lane j+16k.
// D/C layout: DISCOVERED AT RUNTIME via two probe mfmas (robust to any perm).
template <bool RELU>
__global__ __launch_bounds__(256) void conv3x3_mfma(
    const double* __restrict__ in, const float* __restrict__ w,
    const float* __restrict__ bias, double* __restrict__ out, int H, int W) {
  __shared__ double sh[18 * 257];   // 36.99 KB
  const int t = threadIdx.x;
  const int lane = t & 63;
  const int wave = t >> 6;
  const int x0 = blockIdx.x * 16;
  const int y = blockIdx.y;
  const int b = blockIdx.z;
  const int m = lane & 15;      // A row (pixel) / B col (cout) owner index
  const int kq = lane >> 4;     // k slot within mfma K=4

  // ---- probe the D/C register layout ----
  // probe1: A[i][0]=i, B[0][j]=1  => D[i][j]=i  (value = logical row)
  // probe2: A[i][0]=1, B[0][j]=j  => D[i][j]=j  (value = logical col)
  d4 z = {0.0, 0.0, 0.0, 0.0};
  double pa = (kq == 0) ? (double)m : 0.0;   // m on k=0 slots
  double pb = (kq == 0) ? 1.0 : 0.0;         // 1 on k=0 slots
  d4 p1 = __builtin_amdgcn_mfma_f64_16x16x4f64(pa, pb, z, 0, 0, 0);
  d4 p2 = __builtin_amdgcn_mfma_f64_16x16x4f64(pb, pa, z, 0, 0, 0);
  int drow[4], dcol[4];
#pragma unroll
  for (int r = 0; r < 4; ++r) {
    int rr = (int)(p1[r] + 0.5);
    int cc = (int)(p2[r] + 0.5);
    drow[r] = rr < 0 ? 0 : (rr > 15 ? 15 : rr);
    dcol[r] = cc < 0 ? 0 : (cc > 15 ? 15 : cc);
  }

  const int n_base = wave * 64;
  d4 acc[4];
#pragma unroll
  for (int nt = 0; nt < 4; ++nt)
#pragma unroll
    for (int r = 0; r < 4; ++r)
      acc[nt][r] = (double)bias[n_base + nt * 16 + dcol[r]];

  for (int ky = 0; ky < 3; ++ky) {
    const int gy = y + ky - 1;
    __syncthreads();
    // stage input row gy: 18 cols (x0-1 .. x0+16) x 256 ci (thread = ci)
    for (int j = 0; j < 18; ++j) {
      int gx = x0 + j - 1;
      double v = 0.0;
      if (gy >= 0 && gy < H && gx >= 0 && gx < W)
        v = in[(((size_t)b * H + gy) * W + gx) * 256 + t];
      sh[j * 257 + t] = v;
    }
    __syncthreads();
#pragma unroll
    for (int kx = 0; kx < 3; ++kx) {
      const double* arow = sh + (m + kx) * 257 + kq;
      const float* wp = w + (size_t)((ky * 3 + kx) * 256 + kq) * 256 + n_base + m;
      for (int s = 0; s < 64; ++s) {
        double a = arow[s * 4];                      // A[pixel=m][ci=kq+4s]
        const float* wrow = wp + (size_t)(s * 4) * 256;
#pragma unroll
        for (int nt = 0; nt < 4; ++nt) {
          double bv = (double)wrow[nt * 16];          // B[ci=kq+4s][co=n_base+nt*16+m]
          acc[nt] = __builtin_amdgcn_mfma_f64_16x16x4f64(a, bv, acc[nt], 0, 0, 0);
        }
      }
    }
  }
  // D slot (lane, r) holds D[drow[r]][dcol[r]] of each 16x16 tile
#pragma unroll
  for (int nt = 0; nt < 4; ++nt) {
#pragma unroll
    for (int r = 0; r < 4; ++r) {
      int gx = x0 + drow[r];
      if (gx < W) {
        double v = acc[nt][r];
        if (RELU) v = fmax(v, 0.0);
        out[(((size_t)b * H + y) * W + gx) * 256 + n_base + nt * 16 + dcol[r]] = v;
      }
    }
  }
}

// ---------------- RPN head (obj + delta 1x1) + anchor decode, f64 -----------
struct AnchorHW { double hh[9]; double ww[9]; };

__global__ __launch_bounds__(64) void rpn_head_d(
    const double* __restrict__ tmap,
    const float* __restrict__ w_obj, const float* __restrict__ b_obj,
    const float* __restrict__ w_dlt, const float* __restrict__ b_dlt,
    double* __restrict__ scores, double* __restrict__ boxes,
    int H, int W, int a_off, double stride, AnchorHW anc) {
  __shared__ double tv[256];
  __shared__ double dlt[36];
  const int t = threadIdx.x;
  const int x = blockIdx.x, y = blockIdx.y, b = blockIdx.z;
  const double* px = tmap + (((size_t)b * H + y) * W + x) * 256;
  tv[t] = px[t]; tv[t + 64] = px[t + 64]; tv[t + 128] = px[t + 128]; tv[t + 192] = px[t + 192];
  __syncthreads();
  double sacc = 0.0;
  if (t < 9) {
    sacc = (double)b_obj[t];
    for (int ci = 0; ci < 256; ++ci) sacc += tv[ci] * (double)w_obj[ci * 9 + t];
  } else if (t < 45) {
    int j = t - 9;
    double a = (double)b_dlt[j];
    for (int ci = 0; ci < 256; ++ci) a += tv[ci] * (double)w_dlt[ci * 36 + j];
    dlt[j] = a;
  }
  __syncthreads();
  if (t < 9) {
    int ai = a_off + (y * W + x) * 9 + t;
    scores[(size_t)b * NUM_ANCH + ai] = sacc;
    double cy = (y + 0.5) * stride, cx = (x + 0.5) * stride;
    double hh = anc.hh[t], ww = anc.ww[t];
    float ay1 = (float)fmin(fmax(cy - hh * 0.5, 0.0), 512.0);
    float ax1 = (float)fmin(fmax(cx - ww * 0.5, 0.0), 512.0);
    float ay2 = (float)fmin(fmax(cy + hh * 0.5, 0.0), 512.0);
    float ax2 = (float)fmin(fmax(cx + ww * 0.5, 0.0), 512.0);
    float ahf = ay2 - ay1, awf = ax2 - ax1;
    float actyf = ay1 + ahf * 0.5f, actxf = ax1 + awf * 0.5f;
    double dy = dlt[t * 4 + 0], dx = dlt[t * 4 + 1];
    double dh = dlt[t * 4 + 2], dw = dlt[t * 4 + 3];
    double ncy = dy * (double)ahf + (double)actyf;
    double ncx = dx * (double)awf + (double)actxf;
    double nh = exp(dh) * (double)ahf;
    double nw = exp(dw) * (double)awf;
    double* bo = boxes + ((size_t)b * NUM_ANCH + ai) * 4;
    bo[0] = ncy - nh * 0.5;
    bo[1] = ncx - nw * 0.5;
    bo[2] = ncy + nh * 0.5;
    bo[3] = ncx + nw * 0.5;
  }
}

// ---------------- exact top-1000 per batch (f64 radix-select + bitonic) -----
__device__ inline unsigned long long dkey(double f) {
  unsigned long long u = (unsigned long long)__double_as_longlong(f);
  return u ^ ((unsigned long long)((long long)u >> 63) | 0x8000000000000000ull);
}

__global__ __launch_bounds__(1024) void topk_d(
    const double* __restrict__ scores, const double* __restrict__ boxes,
    double* __restrict__ ss, double* __restrict__ sb) {
  const int A = NUM_ANCH;
  __shared__ unsigned hist[256];
  __shared__ unsigned long long kk[2048];
  __shared__ unsigned id[2048];
  __shared__ unsigned long long s_prefix;
  __shared__ unsigned s_need, s_cnt;
  const int b = blockIdx.x, t = threadIdx.x;
  const double* sc = scores + (size_t)b * A;
  if (t == 0) { s_prefix = 0ull; s_need = 1000; s_cnt = 0; }
  __syncthreads();
  for (int r = 0; r < 8; ++r) {
    if (t < 256) hist[t] = 0;
    __syncthreads();
    const int shift = 56 - 8 * r;
    const unsigned long long prefix = s_prefix;
    unsigned long long maskHigh = 0ull;
    if (r != 0) maskHigh = (~0ull) << (shift + 8);
    for (int i = t; i < A; i += 1024) {
      unsigned long long k = dkey(sc[i]);
      if ((k & maskHigh) == prefix) atomicAdd(&hist[(unsigned)(k >> shift) & 255u], 1u);
    }
    __syncthreads();
    if (t == 0) {
      unsigned need = s_need, cum = 0;
      for (int bin = 255; bin >= 0; --bin) {
        cum += hist[bin];
        if (cum >= need) {
          s_prefix = prefix | ((unsigned long long)bin << shift);
          s_need = need - (cum - hist[bin]);
          break;
        }
      }
    }
    __syncthreads();
  }
  const unsigned long long K = s_prefix;
  for (int i = t; i < A; i += 1024) {
    unsigned long long k = dkey(sc[i]);
    if (k >= K) {
      unsigned pos = atomicAdd(&s_cnt, 1u);
      if (pos < 2048) { kk[pos] = k; id[pos] = (unsigned)i; }
    }
  }
  __syncthreads();
  unsigned cnt = s_cnt;
  for (int i = t; i < 2048; i += 1024)
    if (i >= cnt) { kk[i] = 0ull; id[i] = 0xFFFFFFFFu; }
  __syncthreads();
  for (int k = 2; k <= 2048; k <<= 1) {
    for (int j = k >> 1; j > 0; j >>= 1) {
#pragma unroll
      for (int u = 0; u < 2; ++u) {
        int i = t + u * 1024;
        int ixj = i ^ j;
        if (ixj > i) {
          unsigned long long ka = kk[i], kc = kk[ixj];
          unsigned ia = id[i], ic = id[ixj];
          bool cPrec = (kc > ka) || (kc == ka && ic < ia);
          bool up = (i & k) != 0;
          if (cPrec != up) { kk[i] = kc; kk[ixj] = ka; id[i] = ic; id[ixj] = ia; }
        }
      }
      __syncthreads();
    }
  }
  if (t < 1000) {
    unsigned idx = id[t];
    ss[b * 1000 + t] = sc[idx];
    const double* bp = boxes + ((size_t)b * A + idx) * 4;
    double* op = sb + (b * 1000 + t) * 4;
    op[0] = bp[0]; op[1] = bp[1]; op[2] = bp[2]; op[3] = bp[3];
  }
}

// ---------------- suppression bit-matrix (iou>0.7 & j>i), f64 ---------------
__global__ void suppmat_d(const double* __restrict__ sb,
                          unsigned long long* __restrict__ supp) {
  int g = blockIdx.x * 256 + threadIdx.x;   // 32000 = 2*1000*16
  int w = g & 15;
  int i = (g >> 4) % 1000;
  int b = g / 16000;
  const double* bx = sb + b * 4000;
  double y1 = bx[i * 4 + 0], x1 = bx[i * 4 + 1], y2 = bx[i * 4 + 2], x2 = bx[i * 4 + 3];
  double ai = (y2 - y1) * (x2 - x1);
  unsigned long long m = 0;
  for (int q = 0; q < 64; ++q) {
    int j = w * 64 + q;
    if (j > i && j < 1000) {
      double by1 = bx[j * 4 + 0], bx1 = bx[j * 4 + 1], by2 = bx[j * 4 + 2], bx2 = bx[j * 4 + 3];
      double aj = (by2 - by1) * (bx2 - bx1);
      double iy1 = fmax(y1, by1), ix1 = fmax(x1, bx1);
      double iy2 = fmin(y2, by2), ix2 = fmin(x2, bx2);
      double inter = fmax(iy2 - iy1, 0.0) * fmax(ix2 - ix1, 0.0);
      double iou = inter / (ai + aj - inter + 1e-8);
      if (iou > 0.7) m |= (1ull << q);
    }
  }
  supp[g] = m;
}

// ---------------- greedy NMS reduce + slot scatter --------------------------
__global__ __launch_bounds__(64) void nms_reduce_d(
    const double* __restrict__ ss, const double* __restrict__ sb,
    const unsigned long long* __restrict__ supp,
    float* __restrict__ rois, double* __restrict__ rois64) {
  __shared__ unsigned long long aliveS[16];
  __shared__ int pref[16];
  const int b = blockIdx.x, lane = threadIdx.x;
  unsigned long long myword = 0;
  if (lane < 16) {
    for (int q = 0; q < 64; ++q) {
      int j = lane * 64 + q;
      if (j < 1000 && ss[b * 1000 + j] > 0.0) myword |= (1ull << q);
    }
  }
  for (int i = 0; i < 1000; ++i) {
    unsigned long long wv = __shfl(myword, i >> 6);
    if ((wv >> (i & 63)) & 1ull) {
      if (lane < 16) myword &= ~supp[(size_t)b * 16000 + i * 16 + lane];
    }
  }
  if (lane < 16) aliveS[lane] = myword;
  __syncthreads();
  if (lane == 0) {
    int s = 0;
    for (int w = 0; w < 16; ++w) { pref[w] = s; s += __popcll(aliveS[w]); }
  }
  float* ro = rois + b * 4000;
  double* rd = rois64 + b * 4000;
  for (int k = lane; k < 4000; k += 64) { ro[k] = 0.0f; rd[k] = 0.0; }
  __syncthreads();
  for (int j = lane; j < 1000; j += 64) {
    int w = j >> 6;
    unsigned long long word = aliveS[w];
    if ((word >> (j & 63)) & 1ull) {
      unsigned long long below = (j & 63) ? (word & ((1ull << (j & 63)) - 1ull)) : 0ull;
      int slot = pref[w] + __popcll(below);
      const double* bp = sb + (b * 1000 + j) * 4;
      ro[slot * 4 + 0] = (float)bp[0]; ro[slot * 4 + 1] = (float)bp[1];
      ro[slot * 4 + 2] = (float)bp[2]; ro[slot * 4 + 3] = (float)bp[3];
      rd[slot * 4 + 0] = bp[0]; rd[slot * 4 + 1] = bp[1];
      rd[slot * 4 + 2] = bp[2]; rd[slot * 4 + 3] = bp[3];
    }
  }
}

// ---------------- ROI align: f64 sampling of f64 maps -> f32 feats ----------
__global__ __launch_bounds__(256) void roi_align_d(
    const double* __restrict__ o2, const double* __restrict__ o3,
    const double* __restrict__ o4, const double* __restrict__ o5,
    const double* __restrict__ o6, const double* __restrict__ rois64,
    float* __restrict__ feats) {
  __shared__ double s_wy[14], s_wx[14];
  __shared__ int s_y0[14], s_y1[14], s_x0[14], s_x1[14];
  const int t = threadIdx.x;
  const int b = blockIdx.x / 1000, r = blockIdx.x % 1000;
  const double* box = rois64 + (b * 1000 + r) * 4;
  double b0 = box[0], b1 = box[1], b2 = box[2], b3 = box[3];
  double h = b2 - b0, w = b3 - b1;
  double size = sqrt(fmax(h * w, 1e-8));
  double lf = floor(log2(size / 224.0) + 4.0);
  lf = fmin(fmax(lf, 2.0), 6.0);
  int lvl = (int)lf;
  int stride_i = 1 << lvl;
  double stride = (double)stride_i;
  int fs_i = 512 >> lvl;
  double fs = (double)fs_i;
  if (t < 14) {
    double v = b0 / stride + ((t + 0.5) * (h / stride)) / 14.0 - 0.5;
    v = fmin(fmax(v, 0.0), fs - 1.0);
    int i0 = (int)floor(v);
    s_y0[t] = i0; s_y1[t] = min(i0 + 1, fs_i - 1); s_wy[t] = v - (double)i0;
  } else if (t >= 64 && t < 78) {
    int u = t - 64;
    double v = b1 / stride + ((u + 0.5) * (w / stride)) / 14.0 - 0.5;
    v = fmin(fmax(v, 0.0), fs - 1.0);
    int i0 = (int)floor(v);
    s_x0[u] = i0; s_x1[u] = min(i0 + 1, fs_i - 1); s_wx[u] = v - (double)i0;
  }
  __syncthreads();
  const double* omaps[5] = {o2, o3, o4, o5, o6};
  const double* fm = omaps[lvl - 2] + (size_t)b * fs_i * fs_i * 256 + t;
  float* op = feats + ((size_t)(b * 1000 + r) * 49) * 256 + t;
  for (int oy = 0; oy < 7; ++oy) {
    double acc[7] = {0, 0, 0, 0, 0, 0, 0};
#pragma unroll
    for (int sy = 0; sy < 2; ++sy) {
      int yy = oy * 2 + sy;
      int y0 = s_y0[yy], y1 = s_y1[yy];
      double wy = s_wy[yy];
      const double* r0 = fm + (size_t)y0 * fs_i * 256;
      const double* r1 = fm + (size_t)y1 * fs_i * 256;
      for (int ox = 0; ox < 7; ++ox) {
#pragma unroll
        for (int sx = 0; sx < 2; ++sx) {
          int xx = ox * 2 + sx;
          int x0 = s_x0[xx], x1 = s_x1[xx];
          double wx = s_wx[xx];
          double v00 = r0[x0 * 256], v01 = r0[x1 * 256];
          double v10 = r1[x0 * 256], v11 = r1[x1 * 256];
          double val = (1.0 - wy) * ((1.0 - wx) * v00 + wx * v01) +
                       wy * ((1.0 - wx) * v10 + wx * v11);
          acc[ox] += val;
        }
      }
    }
    for (int ox = 0; ox < 7; ++ox)
      op[(oy * 7 + ox) * 256] = (float)(acc[ox] * 0.25);
  }
}

// ---------------- fp32 tiled GEMM 128x64/8x4: C = relu?(A@B + bias) ---------
template <bool RELU>
__global__ __launch_bounds__(256) void gemm_f32(
    const float* __restrict__ A, const float* __restrict__ Bw,
    const float* __restrict__ bias, float* __restrict__ C, int M, int N, int K) {
  __shared__ __align__(16) float As[16][128];
  __shared__ __align__(16) float Bs[16][64];
  const int t = threadIdx.x;
  const int tx = t & 15, ty = t >> 4;
  const int m0 = blockIdx.y * 128, n0 = blockIdx.x * 64;
  float acc[8][4] = {};
  for (int k0 = 0; k0 < K; k0 += 16) {
#pragma unroll
    for (int h = 0; h < 2; ++h) {
      int m = (t >> 2) + h * 64;
      int k4 = (t & 3) * 4;
      float4 v = make_float4(0.f, 0.f, 0.f, 0.f);
      if (m0 + m < M) v = *(const float4*)&A[(size_t)(m0 + m) * K + k0 + k4];
      As[k4 + 0][m] = v.x; As[k4 + 1][m] = v.y; As[k4 + 2][m] = v.z; As[k4 + 3][m] = v.w;
    }
    {
      int k = t >> 4, n4 = tx * 4;
      *(float4*)&Bs[k][n4] = *(const float4*)&Bw[(size_t)(k0 + k) * N + n0 + n4];
    }
    __syncthreads();
#pragma unroll
    for (int kk = 0; kk < 16; ++kk) {
      float4 a0 = *(const float4*)&As[kk][ty * 8];
      float4 a1 = *(const float4*)&As[kk][ty * 8 + 4];
      float4 b0 = *(const float4*)&Bs[kk][tx * 4];
      float a[8] = {a0.x, a0.y, a0.z, a0.w, a1.x, a1.y, a1.z, a1.w};
      float bb[4] = {b0.x, b0.y, b0.z, b0.w};
#pragma unroll
      for (int i2 = 0; i2 < 8; ++i2)
#pragma unroll
        for (int j2 = 0; j2 < 4; ++j2) acc[i2][j2] += a[i2] * bb[j2];
    }
    __syncthreads();
  }
#pragma unroll
  for (int i2 = 0; i2 < 8; ++i2) {
    int m = m0 + ty * 8 + i2;
    if (m < M) {
      float4 v;
      float* vp = (float*)&v;
#pragma unroll
      for (int j2 = 0; j2 < 4; ++j2) {
        float val = acc[i2][j2] + bias[n0 + tx * 4 + j2];
        if (RELU) val = fmaxf(val, 0.0f);
        vp[j2] = val;
      }
      *(float4*)&C[(size_t)m * N + n0 + tx * 4] = v;
    }
  }
}

// ---------------- final box(4) + cls(81) heads, f32 -------------------------
__global__ __launch_bounds__(128) void boxcls_kernel(
    const float* __restrict__ x, const float* __restrict__ w_box,
    const float* __restrict__ b_box, const float* __restrict__ w_cls,
    const float* __restrict__ b_cls, float* __restrict__ out) {
  __shared__ float xv[1024];
  const int t = threadIdx.x;
  const int row = blockIdx.x;
  const float* xp = x + (size_t)row * 1024;
#pragma unroll
  for (int k = 0; k < 8; ++k) xv[k * 128 + t] = xp[k * 128 + t];
  __syncthreads();
  if (t < 4) {
    float acc = b_box[t];
    for (int k = 0; k < 1024; ++k) acc += xv[k] * w_box[k * 4 + t];
    out[8000 + row * 4 + t] = acc;
  } else if (t < 85) {
    int j = t - 4;
    float acc = b_cls[j];
    for (int k = 0; k < 1024; ++k) acc += xv[k] * w_cls[k * 81 + j];
    out[16000 + row * 81 + j] = acc;
  }
}

// ---------------------------------------------------------------------------
extern "C" void kernel_launch(void* const* d_in, const int* in_sizes, int n_in,
                              void* d_out, int out_size, void* d_ws, size_t ws_size,
                              hipStream_t stream) {
  (void)in_sizes; (void)n_in; (void)out_size; (void)ws_size;

  const float* c_in[4] = {(const float*)d_in[0], (const float*)d_in[1],
                          (const float*)d_in[2], (const float*)d_in[3]};
  const float *w_l[5], *b_l[5], *w_o[5], *b_o[5];
  for (int l = 0; l < 5; ++l) {
    w_l[l] = (const float*)d_in[4 + l * 4 + 0];
    b_l[l] = (const float*)d_in[4 + l * 4 + 1];
    w_o[l] = (const float*)d_in[4 + l * 4 + 2];
    b_o[l] = (const float*)d_in[4 + l * 4 + 3];
  }
  const float* w_rpn = (const float*)d_in[24];
  const float* b_rpn = (const float*)d_in[25];
  const float* w_obj = (const float*)d_in[26];
  const float* b_obj = (const float*)d_in[27];
  const float* w_dlt = (const float*)d_in[28];
  const float* b_dlt = (const float*)d_in[29];
  const float* w_fc1 = (const float*)d_in[30];
  const float* b_fc1 = (const float*)d_in[31];
  const float* w_fc2 = (const float*)d_in[32];
  const float* b_fc2 = (const float*)d_in[33];
  const float* w_box = (const float*)d_in[34];
  const float* b_box = (const float*)d_in[35];
  const float* w_cls = (const float*)d_in[36];
  const float* b_cls = (const float*)d_in[37];

  char* W8 = (char*)d_ws;
  double* o64 = (double*)(W8 + 0);
  double* p64 = (double*)(W8 + 89391104);
  float* c6buf = (float*)(W8 + 178782208);
  double* scores = (double*)(W8 + 179830784);
  double* boxes = (double*)(W8 + 182973440);
  double* ssb = (double*)(W8 + 195544064);
  double* sbb = (double*)(W8 + 195560064);
  double* rois64 = (double*)(W8 + 195624064);
  unsigned long long* suppb = (unsigned long long*)(W8 + 195688064);
  float* feats = (float*)(W8 + 89391104);   // overlaps dead p64/c6/scores/boxes
  float* fc1b = (float*)(W8 + 0);           // overlaps dead o64
  float* fc2b = (float*)(W8 + 8192000);
  float* outf = (float*)d_out;

  const size_t OFF[5] = {0, 8388608, 10485760, 11010048, 11141120};
  double* o[5]; double* p[5];
  for (int l = 0; l < 5; ++l) { o[l] = o64 + OFF[l]; p[l] = p64 + OFF[l]; }

  const int HS[5] = {128, 64, 32, 16, 8};
  const int a_off[5] = {0, 147456, 184320, 193536, 195840};
  const double strides[5] = {4.0, 8.0, 16.0, 32.0, 64.0};
  const double SZ[5] = {16.0, 32.0, 64.0, 128.0, 256.0};
  AnchorHW anc[5];
  for (int l = 0; l < 5; ++l) {
    const double ars[3] = {0.5, 1.0, 2.0};
    for (int s = 0; s < 3; ++s) {
      double sc = pow(2.0, s / 3.0);
      for (int a = 0; a < 3; ++a) {
        double sq = sqrt(ars[a]);
        anc[l].hh[s * 3 + a] = SZ[l] * sc / sq;
        anc[l].ww[s * 3 + a] = SZ[l] * sc * sq;
      }
    }
  }

  // ---- FPN (f64) ----
  maxpool_kernel<<<1024, 256, 0, stream>>>(c_in[3], c6buf);
  lateral_d<2048><<<32, 256, 0, stream>>>(c6buf, w_l[4], b_l[4], p[4]);      // p6
  lateral_d<2048><<<128, 256, 0, stream>>>(c_in[3], w_l[3], b_l[3], p[3]);   // p5
  upadd_d<<<512, 256, 0, stream>>>(p[3], p[4], 16, 16);
  lateral_d<1024><<<512, 256, 0, stream>>>(c_in[2], w_l[2], b_l[2], p[2]);   // p4
  upadd_d<<<2048, 256, 0, stream>>>(p[2], p[3], 32, 32);
  lateral_d<512><<<2048, 256, 0, stream>>>(c_in[1], w_l[1], b_l[1], p[1]);   // p3
  upadd_d<<<8192, 256, 0, stream>>>(p[1], p[2], 64, 64);
  lateral_d<256><<<8192, 256, 0, stream>>>(c_in[0], w_l[0], b_l[0], p[0]);   // p2
  upadd_d<<<32768, 256, 0, stream>>>(p[0], p[1], 128, 128);
  for (int l = 0; l < 5; ++l) {
    dim3 g((HS[l] + 15) / 16, HS[l], 2);
    conv3x3_mfma<false><<<g, 256, 0, stream>>>(p[l], w_o[l], b_o[l], o[l], HS[l], HS[l]);
  }
  // ---- RPN head (t-maps reuse p buffers) ----
  for (int l = 0; l < 5; ++l) {
    dim3 g((HS[l] + 15) / 16, HS[l], 2);
    conv3x3_mfma<true><<<g, 256, 0, stream>>>(o[l], w_rpn, b_rpn, p[l], HS[l], HS[l]);
  }
  for (int l = 0; l < 5; ++l) {
    dim3 g(HS[l], HS[l], 2);
    rpn_head_d<<<g, 64, 0, stream>>>(p[l], w_obj, b_obj, w_dlt, b_dlt, scores, boxes,
                                     HS[l], HS[l], a_off[l], strides[l], anc[l]);
  }
  // ---- top-1000 + NMS (f64) ----
  topk_d<<<2, 1024, 0, stream>>>(scores, boxes, ssb, sbb);
  suppmat_d<<<125, 256, 0, stream>>>(sbb, suppb);
  nms_reduce_d<<<2, 64, 0, stream>>>(ssb, sbb, suppb, outf, rois64);
  // ---- ROI align + FC head ----
  roi_align_d<<<2000, 256, 0, stream>>>(o[0], o[1], o[2], o[3], o[4], rois64, feats);
  gemm_f32<true><<<dim3(16, 16), 256, 0, stream>>>(feats, w_fc1, b_fc1, fc1b, 2000, 1024, 12544);
  gemm_f32<true><<<dim3(16, 16), 256, 0, stream>>>(fc1b, w_fc2, b_fc2, fc2b, 2000, 1024, 1024);
  boxcls_kernel<<<2000, 128, 0, stream>>>(fc2b, w_box, b_box, w_cls, b_cls, outf);
}

// Round 5
// 5080.556 us; speedup vs baseline: 1.4046x; 1.2060x over previous
//
#include <hip/hip_runtime.h>
#include <math.h>

// ---------------------------------------------------------------------------
// Faster-RCNN head, fp64 through the rois-determining path. Round 4:
//  - FC GEMMs on bf16 MFMA with hi/lo split (3-mfma trick, f32-equiv precision)
//  - conv3x3 f64 MFMA w/ self-calibrating D-layout (R3, passing) unchanged.
//
// Workspace (BYTES):
//   o64  (double, 11,173,888 el)   [0          .. 89,391,104)
//   p64  (double, 11,173,888 el)   [89,391,104 .. 178,782,208)
//   c6   (float)                   [178,782,208 .. 179,830,784)
//   scores (double)                [179,830,784 .. 182,973,440)
//   boxes  (double)                [182,973,440 .. 195,544,064)
//   ss/sb/rois64/supp tail         [195,544,064 .. 195,944,064)
//   featsH/L (bf16) overlap p64+   [89,391,104 .. 189,743,104)   (after rpn)
//   fc region overlaps o64 (dead after roi_align):
//     fc1b f32  [0 .. 8,192,000)      fc2b f32 [8,192,000 .. 16,384,000)
//     wT1H [16,384,000 .. 42,074,112) wT1L [42,074,112 .. 67,764,224)
//     wT2H [67,764,224 .. 69,861,376) wT2L [69,861,376 .. 71,958,528)
//     fc1H [71,958,528 .. 76,054,528) fc1L [76,054,528 .. 80,150,528)
// ---------------------------------------------------------------------------

#define NUM_ANCH 196416

typedef double d4 __attribute__((ext_vector_type(4)));
typedef __attribute__((ext_vector_type(8))) short bf8_t;
typedef __attribute__((ext_vector_type(4))) float f4_t;

__device__ inline unsigned short f2bf(float x) {
  unsigned u = __float_as_uint(x);
  unsigned r = (u + 0x7fffu + ((u >> 16) & 1u)) >> 16;   // RNE
  return (unsigned short)r;
}
__device__ inline float bf2f(unsigned short h) {
  return __uint_as_float(((unsigned)h) << 16);
}

// ---------------- maxpool2 c5 (2,16,16,2048) -> c6 (2,8,8,2048), f32 --------
__global__ void maxpool_kernel(const float* __restrict__ in, float* __restrict__ out) {
  int idx = blockIdx.x * 256 + threadIdx.x;     // 262144 total
  int c = idx & 2047;
  int x = (idx >> 11) & 7;
  int y = (idx >> 14) & 7;
  int b = idx >> 17;
  const float* p = in + (((size_t)b * 16 + 2 * y) * 16 + 2 * x) * 2048 + c;
  float m = fmaxf(fmaxf(p[0], p[2048]), fmaxf(p[16 * 2048], p[16 * 2048 + 2048]));
  out[idx] = m;
}

// ---------------- 1x1 lateral conv + bias, f32 in -> f64 out ----------------
template <int CIN>
__global__ __launch_bounds__(256) void lateral_d(
    const float* __restrict__ in, const float* __restrict__ w,
    const float* __restrict__ bias, double* __restrict__ out) {
  const int t = threadIdx.x;
  const size_t pix0 = (size_t)blockIdx.x * 4;
  double b = (double)bias[t];
  double a0 = b, a1 = b, a2 = b, a3 = b;
  const float* i0 = in + pix0 * CIN;
  for (int ci = 0; ci < CIN; ++ci) {
    double wv = (double)w[ci * 256 + t];
    a0 += (double)i0[ci] * wv;
    a1 += (double)i0[CIN + ci] * wv;
    a2 += (double)i0[2 * CIN + ci] * wv;
    a3 += (double)i0[3 * CIN + ci] * wv;
  }
  out[(pix0 + 0) * 256 + t] = a0;
  out[(pix0 + 1) * 256 + t] = a1;
  out[(pix0 + 2) * 256 + t] = a2;
  out[(pix0 + 3) * 256 + t] = a3;
}

// ---------------- fine += upsample2(coarse), C=256, f64 ---------------------
__global__ void upadd_d(double* __restrict__ fine, const double* __restrict__ coarse,
                        int Hf, int Wf) {
  int idx = blockIdx.x * 256 + threadIdx.x;
  int c = idx & 255;
  int rem = idx >> 8;
  int x = rem % Wf; rem /= Wf;
  int y = rem % Hf;
  int b = rem / Hf;
  fine[idx] += coarse[(((size_t)b * (Hf >> 1) + (y >> 1)) * (Wf >> 1) + (x >> 1)) * 256 + c];
}

// ---------------- 3x3 SAME conv 256->256 + bias (+relu), f64 MFMA -----------
template <bool RELU>
__global__ __launch_bounds__(256) void conv3x3_mfma(
    const double* __restrict__ in, const float* __restrict__ w,
    const float* __restrict__ bias, double* __restrict__ out, int H, int W) {
  __shared__ double sh[18 * 257];   // 36.99 KB
  const int t = threadIdx.x;
  const int lane = t & 63;
  const int wave = t >> 6;
  const int x0 = blockIdx.x * 16;
  const int y = blockIdx.y;
  const int b = blockIdx.z;
  const int m = lane & 15;      // A row (pixel) / B col (cout) owner index
  const int kq = lane >> 4;     // k slot within mfma K=4

  // probe the D/C register layout (robust to any permutation)
  d4 z = {0.0, 0.0, 0.0, 0.0};
  double pa = (kq == 0) ? (double)m : 0.0;
  double pb = (kq == 0) ? 1.0 : 0.0;
  d4 p1 = __builtin_amdgcn_mfma_f64_16x16x4f64(pa, pb, z, 0, 0, 0);
  d4 p2 = __builtin_amdgcn_mfma_f64_16x16x4f64(pb, pa, z, 0, 0, 0);
  int drow[4], dcol[4];
#pragma unroll
  for (int r = 0; r < 4; ++r) {
    int rr = (int)(p1[r] + 0.5);
    int cc = (int)(p2[r] + 0.5);
    drow[r] = rr < 0 ? 0 : (rr > 15 ? 15 : rr);
    dcol[r] = cc < 0 ? 0 : (cc > 15 ? 15 : cc);
  }

  const int n_base = wave * 64;
  d4 acc[4];
#pragma unroll
  for (int nt = 0; nt < 4; ++nt)
#pragma unroll
    for (int r = 0; r < 4; ++r)
      acc[nt][r] = (double)bias[n_base + nt * 16 + dcol[r]];

  for (int ky = 0; ky < 3; ++ky) {
    const int gy = y + ky - 1;
    __syncthreads();
    for (int j = 0; j < 18; ++j) {
      int gx = x0 + j - 1;
      double v = 0.0;
      if (gy >= 0 && gy < H && gx >= 0 && gx < W)
        v = in[(((size_t)b * H + gy) * W + gx) * 256 + t];
      sh[j * 257 + t] = v;
    }
    __syncthreads();
#pragma unroll
    for (int kx = 0; kx < 3; ++kx) {
      const double* arow = sh + (m + kx) * 257 + kq;
      const float* wp = w + (size_t)((ky * 3 + kx) * 256 + kq) * 256 + n_base + m;
      for (int s = 0; s < 64; ++s) {
        double a = arow[s * 4];
        const float* wrow = wp + (size_t)(s * 4) * 256;
#pragma unroll
        for (int nt = 0; nt < 4; ++nt) {
          double bv = (double)wrow[nt * 16];
          acc[nt] = __builtin_amdgcn_mfma_f64_16x16x4f64(a, bv, acc[nt], 0, 0, 0);
        }
      }
    }
  }
#pragma unroll
  for (int nt = 0; nt < 4; ++nt) {
#pragma unroll
    for (int r = 0; r < 4; ++r) {
      int gx = x0 + drow[r];
      if (gx < W) {
        double v = acc[nt][r];
        if (RELU) v = fmax(v, 0.0);
        out[(((size_t)b * H + y) * W + gx) * 256 + n_base + nt * 16 + dcol[r]] = v;
      }
    }
  }
}

// ---------------- RPN head (obj + delta 1x1) + anchor decode, f64 -----------
struct AnchorHW { double hh[9]; double ww[9]; };

__global__ __launch_bounds__(64) void rpn_head_d(
    const double* __restrict__ tmap,
    const float* __restrict__ w_obj, const float* __restrict__ b_obj,
    const float* __restrict__ w_dlt, const float* __restrict__ b_dlt,
    double* __restrict__ scores, double* __restrict__ boxes,
    int H, int W, int a_off, double stride, AnchorHW anc) {
  __shared__ double tv[256];
  __shared__ double dlt[36];
  const int t = threadIdx.x;
  const int x = blockIdx.x, y = blockIdx.y, b = blockIdx.z;
  const double* px = tmap + (((size_t)b * H + y) * W + x) * 256;
  tv[t] = px[t]; tv[t + 64] = px[t + 64]; tv[t + 128] = px[t + 128]; tv[t + 192] = px[t + 192];
  __syncthreads();
  double sacc = 0.0;
  if (t < 9) {
    sacc = (double)b_obj[t];
    for (int ci = 0; ci < 256; ++ci) sacc += tv[ci] * (double)w_obj[ci * 9 + t];
  } else if (t < 45) {
    int j = t - 9;
    double a = (double)b_dlt[j];
    for (int ci = 0; ci < 256; ++ci) a += tv[ci] * (double)w_dlt[ci * 36 + j];
    dlt[j] = a;
  }
  __syncthreads();
  if (t < 9) {
    int ai = a_off + (y * W + x) * 9 + t;
    scores[(size_t)b * NUM_ANCH + ai] = sacc;
    double cy = (y + 0.5) * stride, cx = (x + 0.5) * stride;
    double hh = anc.hh[t], ww = anc.ww[t];
    float ay1 = (float)fmin(fmax(cy - hh * 0.5, 0.0), 512.0);
    float ax1 = (float)fmin(fmax(cx - ww * 0.5, 0.0), 512.0);
    float ay2 = (float)fmin(fmax(cy + hh * 0.5, 0.0), 512.0);
    float ax2 = (float)fmin(fmax(cx + ww * 0.5, 0.0), 512.0);
    float ahf = ay2 - ay1, awf = ax2 - ax1;
    float actyf = ay1 + ahf * 0.5f, actxf = ax1 + awf * 0.5f;
    double dy = dlt[t * 4 + 0], dx = dlt[t * 4 + 1];
    double dh = dlt[t * 4 + 2], dw = dlt[t * 4 + 3];
    double ncy = dy * (double)ahf + (double)actyf;
    double ncx = dx * (double)awf + (double)actxf;
    double nh = exp(dh) * (double)ahf;
    double nw = exp(dw) * (double)awf;
    double* bo = boxes + ((size_t)b * NUM_ANCH + ai) * 4;
    bo[0] = ncy - nh * 0.5;
    bo[1] = ncx - nw * 0.5;
    bo[2] = ncy + nh * 0.5;
    bo[3] = ncx + nw * 0.5;
  }
}

// ---------------- exact top-1000 per batch (f64 radix-select + bitonic) -----
__device__ inline unsigned long long dkey(double f) {
  unsigned long long u = (unsigned long long)__double_as_longlong(f);
  return u ^ ((unsigned long long)((long long)u >> 63) | 0x8000000000000000ull);
}

__global__ __launch_bounds__(1024) void topk_d(
    const double* __restrict__ scores, const double* __restrict__ boxes,
    double* __restrict__ ss, double* __restrict__ sb) {
  const int A = NUM_ANCH;
  __shared__ unsigned hist[256];
  __shared__ unsigned long long kk[2048];
  __shared__ unsigned id[2048];
  __shared__ unsigned long long s_prefix;
  __shared__ unsigned s_need, s_cnt;
  const int b = blockIdx.x, t = threadIdx.x;
  const double* sc = scores + (size_t)b * A;
  if (t == 0) { s_prefix = 0ull; s_need = 1000; s_cnt = 0; }
  __syncthreads();
  for (int r = 0; r < 8; ++r) {
    if (t < 256) hist[t] = 0;
    __syncthreads();
    const int shift = 56 - 8 * r;
    const unsigned long long prefix = s_prefix;
    unsigned long long maskHigh = 0ull;
    if (r != 0) maskHigh = (~0ull) << (shift + 8);
    for (int i = t; i < A; i += 1024) {
      unsigned long long k = dkey(sc[i]);
      if ((k & maskHigh) == prefix) atomicAdd(&hist[(unsigned)(k >> shift) & 255u], 1u);
    }
    __syncthreads();
    if (t == 0) {
      unsigned need = s_need, cum = 0;
      for (int bin = 255; bin >= 0; --bin) {
        cum += hist[bin];
        if (cum >= need) {
          s_prefix = prefix | ((unsigned long long)bin << shift);
          s_need = need - (cum - hist[bin]);
          break;
        }
      }
    }
    __syncthreads();
  }
  const unsigned long long K = s_prefix;
  for (int i = t; i < A; i += 1024) {
    unsigned long long k = dkey(sc[i]);
    if (k >= K) {
      unsigned pos = atomicAdd(&s_cnt, 1u);
      if (pos < 2048) { kk[pos] = k; id[pos] = (unsigned)i; }
    }
  }
  __syncthreads();
  unsigned cnt = s_cnt;
  for (int i = t; i < 2048; i += 1024)
    if (i >= cnt) { kk[i] = 0ull; id[i] = 0xFFFFFFFFu; }
  __syncthreads();
  for (int k = 2; k <= 2048; k <<= 1) {
    for (int j = k >> 1; j > 0; j >>= 1) {
#pragma unroll
      for (int u = 0; u < 2; ++u) {
        int i = t + u * 1024;
        int ixj = i ^ j;
        if (ixj > i) {
          unsigned long long ka = kk[i], kc = kk[ixj];
          unsigned ia = id[i], ic = id[ixj];
          bool cPrec = (kc > ka) || (kc == ka && ic < ia);
          bool up = (i & k) != 0;
          if (cPrec != up) { kk[i] = kc; kk[ixj] = ka; id[i] = ic; id[ixj] = ia; }
        }
      }
      __syncthreads();
    }
  }
  if (t < 1000) {
    unsigned idx = id[t];
    ss[b * 1000 + t] = sc[idx];
    const double* bp = boxes + ((size_t)b * A + idx) * 4;
    double* op = sb + (b * 1000 + t) * 4;
    op[0] = bp[0]; op[1] = bp[1]; op[2] = bp[2]; op[3] = bp[3];
  }
}

// ---------------- suppression bit-matrix (iou>0.7 & j>i), f64 ---------------
__global__ void suppmat_d(const double* __restrict__ sb,
                          unsigned long long* __restrict__ supp) {
  int g = blockIdx.x * 256 + threadIdx.x;   // 32000 = 2*1000*16
  int w = g & 15;
  int i = (g >> 4) % 1000;
  int b = g / 16000;
  const double* bx = sb + b * 4000;
  double y1 = bx[i * 4 + 0], x1 = bx[i * 4 + 1], y2 = bx[i * 4 + 2], x2 = bx[i * 4 + 3];
  double ai = (y2 - y1) * (x2 - x1);
  unsigned long long m = 0;
  for (int q = 0; q < 64; ++q) {
    int j = w * 64 + q;
    if (j > i && j < 1000) {
      double by1 = bx[j * 4 + 0], bx1 = bx[j * 4 + 1], by2 = bx[j * 4 + 2], bx2 = bx[j * 4 + 3];
      double aj = (by2 - by1) * (bx2 - bx1);
      double iy1 = fmax(y1, by1), ix1 = fmax(x1, bx1);
      double iy2 = fmin(y2, by2), ix2 = fmin(x2, bx2);
      double inter = fmax(iy2 - iy1, 0.0) * fmax(ix2 - ix1, 0.0);
      double iou = inter / (ai + aj - inter + 1e-8);
      if (iou > 0.7) m |= (1ull << q);
    }
  }
  supp[g] = m;
}

// ---------------- greedy NMS reduce + slot scatter --------------------------
__global__ __launch_bounds__(64) void nms_reduce_d(
    const double* __restrict__ ss, const double* __restrict__ sb,
    const unsigned long long* __restrict__ supp,
    float* __restrict__ rois, double* __restrict__ rois64) {
  __shared__ unsigned long long aliveS[16];
  __shared__ int pref[16];
  const int b = blockIdx.x, lane = threadIdx.x;
  unsigned long long myword = 0;
  if (lane < 16) {
    for (int q = 0; q < 64; ++q) {
      int j = lane * 64 + q;
      if (j < 1000 && ss[b * 1000 + j] > 0.0) myword |= (1ull << q);
    }
  }
  for (int i = 0; i < 1000; ++i) {
    unsigned long long wv = __shfl(myword, i >> 6);
    if ((wv >> (i & 63)) & 1ull) {
      if (lane < 16) myword &= ~supp[(size_t)b * 16000 + i * 16 + lane];
    }
  }
  if (lane < 16) aliveS[lane] = myword;
  __syncthreads();
  if (lane == 0) {
    int s = 0;
    for (int w = 0; w < 16; ++w) { pref[w] = s; s += __popcll(aliveS[w]); }
  }
  float* ro = rois + b * 4000;
  double* rd = rois64 + b * 4000;
  for (int k = lane; k < 4000; k += 64) { ro[k] = 0.0f; rd[k] = 0.0; }
  __syncthreads();
  for (int j = lane; j < 1000; j += 64) {
    int w = j >> 6;
    unsigned long long word = aliveS[w];
    if ((word >> (j & 63)) & 1ull) {
      unsigned long long below = (j & 63) ? (word & ((1ull << (j & 63)) - 1ull)) : 0ull;
      int slot = pref[w] + __popcll(below);
      const double* bp = sb + (b * 1000 + j) * 4;
      ro[slot * 4 + 0] = (float)bp[0]; ro[slot * 4 + 1] = (float)bp[1];
      ro[slot * 4 + 2] = (float)bp[2]; ro[slot * 4 + 3] = (float)bp[3];
      rd[slot * 4 + 0] = bp[0]; rd[slot * 4 + 1] = bp[1];
      rd[slot * 4 + 2] = bp[2]; rd[slot * 4 + 3] = bp[3];
    }
  }
}

// ---------------- ROI align: f64 sampling -> hi/lo bf16 feats ---------------
__global__ __launch_bounds__(256) void roi_align_d(
    const double* __restrict__ o2, const double* __restrict__ o3,
    const double* __restrict__ o4, const double* __restrict__ o5,
    const double* __restrict__ o6, const double* __restrict__ rois64,
    unsigned short* __restrict__ featsH, unsigned short* __restrict__ featsL) {
  __shared__ double s_wy[14], s_wx[14];
  __shared__ int s_y0[14], s_y1[14], s_x0[14], s_x1[14];
  const int t = threadIdx.x;
  const int b = blockIdx.x / 1000, r = blockIdx.x % 1000;
  const double* box = rois64 + (b * 1000 + r) * 4;
  double b0 = box[0], b1 = box[1], b2 = box[2], b3 = box[3];
  double h = b2 - b0, w = b3 - b1;
  double size = sqrt(fmax(h * w, 1e-8));
  double lf = floor(log2(size / 224.0) + 4.0);
  lf = fmin(fmax(lf, 2.0), 6.0);
  int lvl = (int)lf;
  int stride_i = 1 << lvl;
  double stride = (double)stride_i;
  int fs_i = 512 >> lvl;
  double fs = (double)fs_i;
  if (t < 14) {
    double v = b0 / stride + ((t + 0.5) * (h / stride)) / 14.0 - 0.5;
    v = fmin(fmax(v, 0.0), fs - 1.0);
    int i0 = (int)floor(v);
    s_y0[t] = i0; s_y1[t] = min(i0 + 1, fs_i - 1); s_wy[t] = v - (double)i0;
  } else if (t >= 64 && t < 78) {
    int u = t - 64;
    double v = b1 / stride + ((u + 0.5) * (w / stride)) / 14.0 - 0.5;
    v = fmin(fmax(v, 0.0), fs - 1.0);
    int i0 = (int)floor(v);
    s_x0[u] = i0; s_x1[u] = min(i0 + 1, fs_i - 1); s_wx[u] = v - (double)i0;
  }
  __syncthreads();
  const double* omaps[5] = {o2, o3, o4, o5, o6};
  const double* fm = omaps[lvl - 2] + (size_t)b * fs_i * fs_i * 256 + t;
  size_t obase = ((size_t)(b * 1000 + r) * 49) * 256 + t;
  for (int oy = 0; oy < 7; ++oy) {
    double acc[7] = {0, 0, 0, 0, 0, 0, 0};
#pragma unroll
    for (int sy = 0; sy < 2; ++sy) {
      int yy = oy * 2 + sy;
      int y0 = s_y0[yy], y1 = s_y1[yy];
      double wy = s_wy[yy];
      const double* r0 = fm + (size_t)y0 * fs_i * 256;
      const double* r1 = fm + (size_t)y1 * fs_i * 256;
      for (int ox = 0; ox < 7; ++ox) {
#pragma unroll
        for (int sx = 0; sx < 2; ++sx) {
          int xx = ox * 2 + sx;
          int x0 = s_x0[xx], x1 = s_x1[xx];
          double wx = s_wx[xx];
          double v00 = r0[x0 * 256], v01 = r0[x1 * 256];
          double v10 = r1[x0 * 256], v11 = r1[x1 * 256];
          double val = (1.0 - wy) * ((1.0 - wx) * v00 + wx * v01) +
                       wy * ((1.0 - wx) * v10 + wx * v11);
          acc[ox] += val;
        }
      }
    }
    for (int ox = 0; ox < 7; ++ox) {
      float v = (float)(acc[ox] * 0.25);
      unsigned short hh = f2bf(v);
      size_t idx = obase + (size_t)(oy * 7 + ox) * 256;
      featsH[idx] = hh;
      featsL[idx] = f2bf(v - bf2f(hh));
    }
  }
}

// ---------------- split f32 [K][N] -> bf16 hi/lo transposed [N][K] ----------
__global__ __launch_bounds__(256) void split_transpose(
    const float* __restrict__ W, unsigned short* __restrict__ TH,
    unsigned short* __restrict__ TL, int K, int N) {
  __shared__ unsigned short shh[32 * 33], shl[32 * 33];
  const int kt = blockIdx.y * 32, nt = blockIdx.x * 32;
  const int tx = threadIdx.x & 31, ty = threadIdx.x >> 5;   // 32x8
  for (int yy = ty; yy < 32; yy += 8) {
    float v = W[(size_t)(kt + yy) * N + nt + tx];
    unsigned short h = f2bf(v);
    shh[yy * 33 + tx] = h;
    shl[yy * 33 + tx] = f2bf(v - bf2f(h));
  }
  __syncthreads();
  for (int yy = ty; yy < 32; yy += 8) {
    TH[(size_t)(nt + yy) * K + kt + tx] = shh[tx * 33 + yy];
    TL[(size_t)(nt + yy) * K + kt + tx] = shl[tx * 33 + yy];
  }
}

// ---------------- split f32 rows -> bf16 hi/lo (no transpose) ---------------
__global__ void split_rows(const float* __restrict__ X, unsigned short* __restrict__ H,
                           unsigned short* __restrict__ L, int n) {
  int i = blockIdx.x * 256 + threadIdx.x;
  if (i < n) {
    float v = X[i];
    unsigned short h = f2bf(v);
    H[i] = h;
    L[i] = f2bf(v - bf2f(h));
  }
}

// ---------------- split-bf16 MFMA GEMM: C = relu?(A@B + bias) ---------------
// A (hi/lo) [M][K] bf16, BT (hi/lo) [N][K] bf16. Tile 64(M)x128(N), BK=32.
// 4 waves: wave w -> m-half w&1 (32 rows), n-half w>>1 (64 cols); per wave
// 2x4 tiles of 16x16, 3 mfma each (aH*bH + aH*bL + aL*bH).
template <bool RELU>
__global__ __launch_bounds__(256) void gemm_mfma_split(
    const unsigned short* __restrict__ AH, const unsigned short* __restrict__ AL,
    const unsigned short* __restrict__ BTH, const unsigned short* __restrict__ BTL,
    const float* __restrict__ bias, float* __restrict__ C, int M, int N, int K) {
  __shared__ __align__(16) unsigned short AsH[64 * 40], AsL[64 * 40];
  __shared__ __align__(16) unsigned short BsH[128 * 40], BsL[128 * 40];
  const int t = threadIdx.x;
  const int lane = t & 63;
  const int wave = t >> 6;
  const int lm = lane & 15, lq = lane >> 4;
  const int wm = wave & 1, wn = wave >> 1;
  const int m0 = blockIdx.y * 64, n0 = blockIdx.x * 128;
  const int sr = t >> 2;            // 0..63
  const int sk = (t & 3) * 8;       // 0,8,16,24

  f4_t acc[2][4];
#pragma unroll
  for (int mt = 0; mt < 2; ++mt)
#pragma unroll
    for (int nt = 0; nt < 4; ++nt) acc[mt][nt] = (f4_t){0.f, 0.f, 0.f, 0.f};

  const uint4 zz = {0u, 0u, 0u, 0u};
  for (int k0 = 0; k0 < K; k0 += 32) {
    __syncthreads();
    // stage A 64x32 (hi/lo)
    {
      uint4 vh = zz, vl = zz;
      if (m0 + sr < M) {
        size_t off = (size_t)(m0 + sr) * K + k0 + sk;
        vh = *(const uint4*)&AH[off];
        vl = *(const uint4*)&AL[off];
      }
      *(uint4*)&AsH[sr * 40 + sk] = vh;
      *(uint4*)&AsL[sr * 40 + sk] = vl;
    }
    // stage B 128x32 (hi/lo), rows n0..n0+127 of BT
#pragma unroll
    for (int hh = 0; hh < 2; ++hh) {
      int row = sr + 64 * hh;
      size_t off = (size_t)(n0 + row) * K + k0 + sk;
      *(uint4*)&BsH[row * 40 + sk] = *(const uint4*)&BTH[off];
      *(uint4*)&BsL[row * 40 + sk] = *(const uint4*)&BTL[off];
    }
    __syncthreads();

    bf8_t aH[2], aL[2], bH[4], bL[4];
#pragma unroll
    for (int mt = 0; mt < 2; ++mt) {
      int idx = (wm * 32 + mt * 16 + lm) * 40 + lq * 8;
      aH[mt] = *(const bf8_t*)&AsH[idx];
      aL[mt] = *(const bf8_t*)&AsL[idx];
    }
#pragma unroll
    for (int nt = 0; nt < 4; ++nt) {
      int idx = (wn * 64 + nt * 16 + lm) * 40 + lq * 8;
      bH[nt] = *(const bf8_t*)&BsH[idx];
      bL[nt] = *(const bf8_t*)&BsL[idx];
    }
#pragma unroll
    for (int mt = 0; mt < 2; ++mt)
#pragma unroll
      for (int nt = 0; nt < 4; ++nt) {
        f4_t a0 = acc[mt][nt];
        a0 = __builtin_amdgcn_mfma_f32_16x16x32_bf16(aL[mt], bH[nt], a0, 0, 0, 0);
        a0 = __builtin_amdgcn_mfma_f32_16x16x32_bf16(aH[mt], bL[nt], a0, 0, 0, 0);
        a0 = __builtin_amdgcn_mfma_f32_16x16x32_bf16(aH[mt], bH[nt], a0, 0, 0, 0);
        acc[mt][nt] = a0;
      }
  }
  // D layout (verified 16x16): col = lane&15, row = (lane>>4)*4 + reg
#pragma unroll
  for (int mt = 0; mt < 2; ++mt) {
#pragma unroll
    for (int nt = 0; nt < 4; ++nt) {
      int ncol = n0 + wn * 64 + nt * 16 + lm;
      float bb = bias[ncol];
#pragma unroll
      for (int r = 0; r < 4; ++r) {
        int m = m0 + wm * 32 + mt * 16 + lq * 4 + r;
        if (m < M) {
          float v = acc[mt][nt][r] + bb;
          if (RELU) v = fmaxf(v, 0.0f);
          C[(size_t)m * N + ncol] = v;
        }
      }
    }
  }
}

// ---------------- final box(4) + cls(81) heads, f32 -------------------------
__global__ __launch_bounds__(128) void boxcls_kernel(
    const float* __restrict__ x, const float* __restrict__ w_box,
    const float* __restrict__ b_box, const float* __restrict__ w_cls,
    const float* __restrict__ b_cls, float* __restrict__ out) {
  __shared__ float xv[1024];
  const int t = threadIdx.x;
  const int row = blockIdx.x;
  const float* xp = x + (size_t)row * 1024;
#pragma unroll
  for (int k = 0; k < 8; ++k) xv[k * 128 + t] = xp[k * 128 + t];
  __syncthreads();
  if (t < 4) {
    float acc = b_box[t];
    for (int k = 0; k < 1024; ++k) acc += xv[k] * w_box[k * 4 + t];
    out[8000 + row * 4 + t] = acc;
  } else if (t < 85) {
    int j = t - 4;
    float acc = b_cls[j];
    for (int k = 0; k < 1024; ++k) acc += xv[k] * w_cls[k * 81 + j];
    out[16000 + row * 81 + j] = acc;
  }
}

// ---------------------------------------------------------------------------
extern "C" void kernel_launch(void* const* d_in, const int* in_sizes, int n_in,
                              void* d_out, int out_size, void* d_ws, size_t ws_size,
                              hipStream_t stream) {
  (void)in_sizes; (void)n_in; (void)out_size; (void)ws_size;

  const float* c_in[4] = {(const float*)d_in[0], (const float*)d_in[1],
                          (const float*)d_in[2], (const float*)d_in[3]};
  const float *w_l[5], *b_l[5], *w_o[5], *b_o[5];
  for (int l = 0; l < 5; ++l) {
    w_l[l] = (const float*)d_in[4 + l * 4 + 0];
    b_l[l] = (const float*)d_in[4 + l * 4 + 1];
    w_o[l] = (const float*)d_in[4 + l * 4 + 2];
    b_o[l] = (const float*)d_in[4 + l * 4 + 3];
  }
  const float* w_rpn = (const float*)d_in[24];
  const float* b_rpn = (const float*)d_in[25];
  const float* w_obj = (const float*)d_in[26];
  const float* b_obj = (const float*)d_in[27];
  const float* w_dlt = (const float*)d_in[28];
  const float* b_dlt = (const float*)d_in[29];
  const float* w_fc1 = (const float*)d_in[30];
  const float* b_fc1 = (const float*)d_in[31];
  const float* w_fc2 = (const float*)d_in[32];
  const float* b_fc2 = (const float*)d_in[33];
  const float* w_box = (const float*)d_in[34];
  const float* b_box = (const float*)d_in[35];
  const float* w_cls = (const float*)d_in[36];
  const float* b_cls = (const float*)d_in[37];

  char* W8 = (char*)d_ws;
  double* o64 = (double*)(W8 + 0);
  double* p64 = (double*)(W8 + 89391104);
  float* c6buf = (float*)(W8 + 178782208);
  double* scores = (double*)(W8 + 179830784);
  double* boxes = (double*)(W8 + 182973440);
  double* ssb = (double*)(W8 + 195544064);
  double* sbb = (double*)(W8 + 195560064);
  double* rois64 = (double*)(W8 + 195624064);
  unsigned long long* suppb = (unsigned long long*)(W8 + 195688064);
  // feats hi/lo overlap dead p64/c6/scores/boxes region
  unsigned short* featsH = (unsigned short*)(W8 + 89391104);   // 50,176,000 B
  unsigned short* featsL = (unsigned short*)(W8 + 139567104);  // 50,176,000 B
  // fc region overlaps dead o64 region (after roi_align)
  float* fc1b = (float*)(W8 + 0);
  float* fc2b = (float*)(W8 + 8192000);
  unsigned short* wT1H = (unsigned short*)(W8 + 16384000);
  unsigned short* wT1L = (unsigned short*)(W8 + 42074112);
  unsigned short* wT2H = (unsigned short*)(W8 + 67764224);
  unsigned short* wT2L = (unsigned short*)(W8 + 69861376);
  unsigned short* fc1H = (unsigned short*)(W8 + 71958528);
  unsigned short* fc1L = (unsigned short*)(W8 + 76054528);
  float* outf = (float*)d_out;

  const size_t OFF[5] = {0, 8388608, 10485760, 11010048, 11141120};
  double* o[5]; double* p[5];
  for (int l = 0; l < 5; ++l) { o[l] = o64 + OFF[l]; p[l] = p64 + OFF[l]; }

  const int HS[5] = {128, 64, 32, 16, 8};
  const int a_off[5] = {0, 147456, 184320, 193536, 195840};
  const double strides[5] = {4.0, 8.0, 16.0, 32.0, 64.0};
  const double SZ[5] = {16.0, 32.0, 64.0, 128.0, 256.0};
  AnchorHW anc[5];
  for (int l = 0; l < 5; ++l) {
    const double ars[3] = {0.5, 1.0, 2.0};
    for (int s = 0; s < 3; ++s) {
      double sc = pow(2.0, s / 3.0);
      for (int a = 0; a < 3; ++a) {
        double sq = sqrt(ars[a]);
        anc[l].hh[s * 3 + a] = SZ[l] * sc / sq;
        anc[l].ww[s * 3 + a] = SZ[l] * sc * sq;
      }
    }
  }

  // ---- FPN (f64) ----
  maxpool_kernel<<<1024, 256, 0, stream>>>(c_in[3], c6buf);
  lateral_d<2048><<<32, 256, 0, stream>>>(c6buf, w_l[4], b_l[4], p[4]);      // p6
  lateral_d<2048><<<128, 256, 0, stream>>>(c_in[3], w_l[3], b_l[3], p[3]);   // p5
  upadd_d<<<512, 256, 0, stream>>>(p[3], p[4], 16, 16);
  lateral_d<1024><<<512, 256, 0, stream>>>(c_in[2], w_l[2], b_l[2], p[2]);   // p4
  upadd_d<<<2048, 256, 0, stream>>>(p[2], p[3], 32, 32);
  lateral_d<512><<<2048, 256, 0, stream>>>(c_in[1], w_l[1], b_l[1], p[1]);   // p3
  upadd_d<<<8192, 256, 0, stream>>>(p[1], p[2], 64, 64);
  lateral_d<256><<<8192, 256, 0, stream>>>(c_in[0], w_l[0], b_l[0], p[0]);   // p2
  upadd_d<<<32768, 256, 0, stream>>>(p[0], p[1], 128, 128);
  for (int l = 0; l < 5; ++l) {
    dim3 g((HS[l] + 15) / 16, HS[l], 2);
    conv3x3_mfma<false><<<g, 256, 0, stream>>>(p[l], w_o[l], b_o[l], o[l], HS[l], HS[l]);
  }
  // ---- RPN head (t-maps reuse p buffers) ----
  for (int l = 0; l < 5; ++l) {
    dim3 g((HS[l] + 15) / 16, HS[l], 2);
    conv3x3_mfma<true><<<g, 256, 0, stream>>>(o[l], w_rpn, b_rpn, p[l], HS[l], HS[l]);
  }
  for (int l = 0; l < 5; ++l) {
    dim3 g(HS[l], HS[l], 2);
    rpn_head_d<<<g, 64, 0, stream>>>(p[l], w_obj, b_obj, w_dlt, b_dlt, scores, boxes,
                                     HS[l], HS[l], a_off[l], strides[l], anc[l]);
  }
  // ---- top-1000 + NMS (f64) ----
  topk_d<<<2, 1024, 0, stream>>>(scores, boxes, ssb, sbb);
  suppmat_d<<<125, 256, 0, stream>>>(sbb, suppb);
  nms_reduce_d<<<2, 64, 0, stream>>>(ssb, sbb, suppb, outf, rois64);
  // ---- ROI align (emits hi/lo bf16 feats) ----
  roi_align_d<<<2000, 256, 0, stream>>>(o[0], o[1], o[2], o[3], o[4], rois64,
                                        featsH, featsL);
  // ---- FC head: split weights (o64 now dead), then MFMA GEMMs ----
  split_transpose<<<dim3(32, 392), 256, 0, stream>>>(w_fc1, wT1H, wT1L, 12544, 1024);
  split_transpose<<<dim3(32, 32), 256, 0, stream>>>(w_fc2, wT2H, wT2L, 1024, 1024);
  gemm_mfma_split<true><<<dim3(8, 32), 256, 0, stream>>>(
      featsH, featsL, wT1H, wT1L, b_fc1, fc1b, 2000, 1024, 12544);
  split_rows<<<8000, 256, 0, stream>>>(fc1b, fc1H, fc1L, 2048000);
  gemm_mfma_split<true><<<dim3(8, 32), 256, 0, stream>>>(
      fc1H, fc1L, wT2H, wT2L, b_fc2, fc2b, 2000, 1024, 1024);
  boxcls_kernel<<<2000, 128, 0, stream>>>(fc2b, w_box, b_box, w_cls, b_cls, outf);
}

// Round 6
// 4694.144 us; speedup vs baseline: 1.5202x; 1.0823x over previous
//
#include <hip/hip_runtime.h>
#include <math.h>

// ---------------------------------------------------------------------------
// Faster-RCNN head, fp64 through the rois-determining path. Round 5:
//  - ALL 5 FPN levels of each 3x3-conv pass fused into ONE dispatch so the
//    small-level blocks (128/32/16 blocks vs 256 CUs) run concurrently with
//    the level-2 stream instead of serially on an idle GPU.
//  - fc GEMM retiled to 128x128 (halves B re-reads).
//  - conv f64 MFMA w/ self-calibrating D-layout (R3) and split-bf16 fc (R4)
//    otherwise unchanged; per-output arithmetic bit-identical.
//
// Workspace (BYTES):
//   o64  (double, 11,173,888 el)   [0          .. 89,391,104)
//   p64  (double, 11,173,888 el)   [89,391,104 .. 178,782,208)
//   c6   (float)                   [178,782,208 .. 179,830,784)
//   scores (double)                [179,830,784 .. 182,973,440)
//   boxes  (double)                [182,973,440 .. 195,544,064)
//   ss/sb/rois64/supp tail         [195,544,064 .. 195,944,064)
//   featsH/L (bf16) overlap p64+   [89,391,104 .. 189,743,104)   (after rpn)
//   fc region overlaps o64 (dead after roi_align):
//     fc1b f32  [0 .. 8,192,000)      fc2b f32 [8,192,000 .. 16,384,000)
//     wT1H [16,384,000 .. 42,074,112) wT1L [42,074,112 .. 67,764,224)
//     wT2H [67,764,224 .. 69,861,376) wT2L [69,861,376 .. 71,958,528)
//     fc1H [71,958,528 .. 76,054,528) fc1L [76,054,528 .. 80,150,528)
// ---------------------------------------------------------------------------

#define NUM_ANCH 196416

typedef double d4 __attribute__((ext_vector_type(4)));
typedef __attribute__((ext_vector_type(8))) short bf8_t;
typedef __attribute__((ext_vector_type(4))) float f4_t;

__device__ inline unsigned short f2bf(float x) {
  unsigned u = __float_as_uint(x);
  unsigned r = (u + 0x7fffu + ((u >> 16) & 1u)) >> 16;   // RNE
  return (unsigned short)r;
}
__device__ inline float bf2f(unsigned short h) {
  return __uint_as_float(((unsigned)h) << 16);
}

// ---------------- maxpool2 c5 (2,16,16,2048) -> c6 (2,8,8,2048), f32 --------
__global__ void maxpool_kernel(const float* __restrict__ in, float* __restrict__ out) {
  int idx = blockIdx.x * 256 + threadIdx.x;     // 262144 total
  int c = idx & 2047;
  int x = (idx >> 11) & 7;
  int y = (idx >> 14) & 7;
  int b = idx >> 17;
  const float* p = in + (((size_t)b * 16 + 2 * y) * 16 + 2 * x) * 2048 + c;
  float m = fmaxf(fmaxf(p[0], p[2048]), fmaxf(p[16 * 2048], p[16 * 2048 + 2048]));
  out[idx] = m;
}

// ---------------- 1x1 lateral conv + bias, f32 in -> f64 out ----------------
template <int CIN>
__global__ __launch_bounds__(256) void lateral_d(
    const float* __restrict__ in, const float* __restrict__ w,
    const float* __restrict__ bias, double* __restrict__ out) {
  const int t = threadIdx.x;
  const size_t pix0 = (size_t)blockIdx.x * 4;
  double b = (double)bias[t];
  double a0 = b, a1 = b, a2 = b, a3 = b;
  const float* i0 = in + pix0 * CIN;
  for (int ci = 0; ci < CIN; ++ci) {
    double wv = (double)w[ci * 256 + t];
    a0 += (double)i0[ci] * wv;
    a1 += (double)i0[CIN + ci] * wv;
    a2 += (double)i0[2 * CIN + ci] * wv;
    a3 += (double)i0[3 * CIN + ci] * wv;
  }
  out[(pix0 + 0) * 256 + t] = a0;
  out[(pix0 + 1) * 256 + t] = a1;
  out[(pix0 + 2) * 256 + t] = a2;
  out[(pix0 + 3) * 256 + t] = a3;
}

// ---------------- fine += upsample2(coarse), C=256, f64 ---------------------
__global__ void upadd_d(double* __restrict__ fine, const double* __restrict__ coarse,
                        int Hf, int Wf) {
  int idx = blockIdx.x * 256 + threadIdx.x;
  int c = idx & 255;
  int rem = idx >> 8;
  int x = rem % Wf; rem /= Wf;
  int y = rem % Hf;
  int b = rem / Hf;
  fine[idx] += coarse[(((size_t)b * (Hf >> 1) + (y >> 1)) * (Wf >> 1) + (x >> 1)) * 256 + c];
}

// ---------------- fused 5-level 3x3 conv, f64 MFMA --------------------------
// One dispatch covers all FPN levels; blockIdx.x -> (level, x-tile, y, batch)
// via the offset table. Per-level math identical to R4's conv3x3_mfma.
struct Conv5Args {
  const double* in[5];
  double* out[5];
  const float* w[5];
  const float* b[5];
  int H[5];
  int nbx[5];
  int off[6];
};

template <bool RELU>
__global__ __launch_bounds__(256) void conv3x3_fused(Conv5Args A) {
  __shared__ double sh[18 * 257];   // 36.99 KB
  const int bx = blockIdx.x;
  int l = 0;
#pragma unroll
  for (int i = 1; i < 5; ++i)
    if (bx >= A.off[i]) l = i;
  const int rel = bx - A.off[l];
  const int H = A.H[l];
  const int nbx = A.nbx[l];
  const int x0 = (rel % nbx) * 16;
  const int y = (rel / nbx) % H;
  const int b = rel / (nbx * H);
  const double* __restrict__ in = A.in[l];
  double* __restrict__ out = A.out[l];
  const float* __restrict__ w = A.w[l];
  const float* __restrict__ bias = A.b[l];
  const int W = H;

  const int t = threadIdx.x;
  const int lane = t & 63;
  const int wave = t >> 6;
  const int m = lane & 15;      // A row (pixel) / B col (cout) owner index
  const int kq = lane >> 4;     // k slot within mfma K=4

  // probe the D/C register layout (robust to any permutation)
  d4 z = {0.0, 0.0, 0.0, 0.0};
  double pa = (kq == 0) ? (double)m : 0.0;
  double pb = (kq == 0) ? 1.0 : 0.0;
  d4 p1 = __builtin_amdgcn_mfma_f64_16x16x4f64(pa, pb, z, 0, 0, 0);
  d4 p2 = __builtin_amdgcn_mfma_f64_16x16x4f64(pb, pa, z, 0, 0, 0);
  int drow[4], dcol[4];
#pragma unroll
  for (int r = 0; r < 4; ++r) {
    int rr = (int)(p1[r] + 0.5);
    int cc = (int)(p2[r] + 0.5);
    drow[r] = rr < 0 ? 0 : (rr > 15 ? 15 : rr);
    dcol[r] = cc < 0 ? 0 : (cc > 15 ? 15 : cc);
  }

  const int n_base = wave * 64;
  d4 acc[4];
#pragma unroll
  for (int nt = 0; nt < 4; ++nt)
#pragma unroll
    for (int r = 0; r < 4; ++r)
      acc[nt][r] = (double)bias[n_base + nt * 16 + dcol[r]];

  for (int ky = 0; ky < 3; ++ky) {
    const int gy = y + ky - 1;
    __syncthreads();
    for (int j = 0; j < 18; ++j) {
      int gx = x0 + j - 1;
      double v = 0.0;
      if (gy >= 0 && gy < H && gx >= 0 && gx < W)
        v = in[(((size_t)b * H + gy) * W + gx) * 256 + t];
      sh[j * 257 + t] = v;
    }
    __syncthreads();
#pragma unroll
    for (int kx = 0; kx < 3; ++kx) {
      const double* arow = sh + (m + kx) * 257 + kq;
      const float* wp = w + (size_t)((ky * 3 + kx) * 256 + kq) * 256 + n_base + m;
      for (int s = 0; s < 64; ++s) {
        double a = arow[s * 4];
        const float* wrow = wp + (size_t)(s * 4) * 256;
#pragma unroll
        for (int nt = 0; nt < 4; ++nt) {
          double bv = (double)wrow[nt * 16];
          acc[nt] = __builtin_amdgcn_mfma_f64_16x16x4f64(a, bv, acc[nt], 0, 0, 0);
        }
      }
    }
  }
#pragma unroll
  for (int nt = 0; nt < 4; ++nt) {
#pragma unroll
    for (int r = 0; r < 4; ++r) {
      int gx = x0 + drow[r];
      if (gx < W) {
        double v = acc[nt][r];
        if (RELU) v = fmax(v, 0.0);
        out[(((size_t)b * H + y) * W + gx) * 256 + n_base + nt * 16 + dcol[r]] = v;
      }
    }
  }
}

// ---------------- RPN head (obj + delta 1x1) + anchor decode, f64 -----------
struct AnchorHW { double hh[9]; double ww[9]; };

__global__ __launch_bounds__(64) void rpn_head_d(
    const double* __restrict__ tmap,
    const float* __restrict__ w_obj, const float* __restrict__ b_obj,
    const float* __restrict__ w_dlt, const float* __restrict__ b_dlt,
    double* __restrict__ scores, double* __restrict__ boxes,
    int H, int W, int a_off, double stride, AnchorHW anc) {
  __shared__ double tv[256];
  __shared__ double dlt[36];
  const int t = threadIdx.x;
  const int x = blockIdx.x, y = blockIdx.y, b = blockIdx.z;
  const double* px = tmap + (((size_t)b * H + y) * W + x) * 256;
  tv[t] = px[t]; tv[t + 64] = px[t + 64]; tv[t + 128] = px[t + 128]; tv[t + 192] = px[t + 192];
  __syncthreads();
  double sacc = 0.0;
  if (t < 9) {
    sacc = (double)b_obj[t];
    for (int ci = 0; ci < 256; ++ci) sacc += tv[ci] * (double)w_obj[ci * 9 + t];
  } else if (t < 45) {
    int j = t - 9;
    double a = (double)b_dlt[j];
    for (int ci = 0; ci < 256; ++ci) a += tv[ci] * (double)w_dlt[ci * 36 + j];
    dlt[j] = a;
  }
  __syncthreads();
  if (t < 9) {
    int ai = a_off + (y * W + x) * 9 + t;
    scores[(size_t)b * NUM_ANCH + ai] = sacc;
    double cy = (y + 0.5) * stride, cx = (x + 0.5) * stride;
    double hh = anc.hh[t], ww = anc.ww[t];
    float ay1 = (float)fmin(fmax(cy - hh * 0.5, 0.0), 512.0);
    float ax1 = (float)fmin(fmax(cx - ww * 0.5, 0.0), 512.0);
    float ay2 = (float)fmin(fmax(cy + hh * 0.5, 0.0), 512.0);
    float ax2 = (float)fmin(fmax(cx + ww * 0.5, 0.0), 512.0);
    float ahf = ay2 - ay1, awf = ax2 - ax1;
    float actyf = ay1 + ahf * 0.5f, actxf = ax1 + awf * 0.5f;
    double dy = dlt[t * 4 + 0], dx = dlt[t * 4 + 1];
    double dh = dlt[t * 4 + 2], dw = dlt[t * 4 + 3];
    double ncy = dy * (double)ahf + (double)actyf;
    double ncx = dx * (double)awf + (double)actxf;
    double nh = exp(dh) * (double)ahf;
    double nw = exp(dw) * (double)awf;
    double* bo = boxes + ((size_t)b * NUM_ANCH + ai) * 4;
    bo[0] = ncy - nh * 0.5;
    bo[1] = ncx - nw * 0.5;
    bo[2] = ncy + nh * 0.5;
    bo[3] = ncx + nw * 0.5;
  }
}

// ---------------- exact top-1000 per batch (f64 radix-select + bitonic) -----
__device__ inline unsigned long long dkey(double f) {
  unsigned long long u = (unsigned long long)__double_as_longlong(f);
  return u ^ ((unsigned long long)((long long)u >> 63) | 0x8000000000000000ull);
}

__global__ __launch_bounds__(1024) void topk_d(
    const double* __restrict__ scores, const double* __restrict__ boxes,
    double* __restrict__ ss, double* __restrict__ sb) {
  const int A = NUM_ANCH;
  __shared__ unsigned hist[256];
  __shared__ unsigned long long kk[2048];
  __shared__ unsigned id[2048];
  __shared__ unsigned long long s_prefix;
  __shared__ unsigned s_need, s_cnt;
  const int b = blockIdx.x, t = threadIdx.x;
  const double* sc = scores + (size_t)b * A;
  if (t == 0) { s_prefix = 0ull; s_need = 1000; s_cnt = 0; }
  __syncthreads();
  for (int r = 0; r < 8; ++r) {
    if (t < 256) hist[t] = 0;
    __syncthreads();
    const int shift = 56 - 8 * r;
    const unsigned long long prefix = s_prefix;
    unsigned long long maskHigh = 0ull;
    if (r != 0) maskHigh = (~0ull) << (shift + 8);
    for (int i = t; i < A; i += 1024) {
      unsigned long long k = dkey(sc[i]);
      if ((k & maskHigh) == prefix) atomicAdd(&hist[(unsigned)(k >> shift) & 255u], 1u);
    }
    __syncthreads();
    if (t == 0) {
      unsigned need = s_need, cum = 0;
      for (int bin = 255; bin >= 0; --bin) {
        cum += hist[bin];
        if (cum >= need) {
          s_prefix = prefix | ((unsigned long long)bin << shift);
          s_need = need - (cum - hist[bin]);
          break;
        }
      }
    }
    __syncthreads();
  }
  const unsigned long long K = s_prefix;
  for (int i = t; i < A; i += 1024) {
    unsigned long long k = dkey(sc[i]);
    if (k >= K) {
      unsigned pos = atomicAdd(&s_cnt, 1u);
      if (pos < 2048) { kk[pos] = k; id[pos] = (unsigned)i; }
    }
  }
  __syncthreads();
  unsigned cnt = s_cnt;
  for (int i = t; i < 2048; i += 1024)
    if (i >= cnt) { kk[i] = 0ull; id[i] = 0xFFFFFFFFu; }
  __syncthreads();
  for (int k = 2; k <= 2048; k <<= 1) {
    for (int j = k >> 1; j > 0; j >>= 1) {
#pragma unroll
      for (int u = 0; u < 2; ++u) {
        int i = t + u * 1024;
        int ixj = i ^ j;
        if (ixj > i) {
          unsigned long long ka = kk[i], kc = kk[ixj];
          unsigned ia = id[i], ic = id[ixj];
          bool cPrec = (kc > ka) || (kc == ka && ic < ia);
          bool up = (i & k) != 0;
          if (cPrec != up) { kk[i] = kc; kk[ixj] = ka; id[i] = ic; id[ixj] = ia; }
        }
      }
      __syncthreads();
    }
  }
  if (t < 1000) {
    unsigned idx = id[t];
    ss[b * 1000 + t] = sc[idx];
    const double* bp = boxes + ((size_t)b * A + idx) * 4;
    double* op = sb + (b * 1000 + t) * 4;
    op[0] = bp[0]; op[1] = bp[1]; op[2] = bp[2]; op[3] = bp[3];
  }
}

// ---------------- suppression bit-matrix (iou>0.7 & j>i), f64 ---------------
__global__ void suppmat_d(const double* __restrict__ sb,
                          unsigned long long* __restrict__ supp) {
  int g = blockIdx.x * 256 + threadIdx.x;   // 32000 = 2*1000*16
  int w = g & 15;
  int i = (g >> 4) % 1000;
  int b = g / 16000;
  const double* bx = sb + b * 4000;
  double y1 = bx[i * 4 + 0], x1 = bx[i * 4 + 1], y2 = bx[i * 4 + 2], x2 = bx[i * 4 + 3];
  double ai = (y2 - y1) * (x2 - x1);
  unsigned long long m = 0;
  for (int q = 0; q < 64; ++q) {
    int j = w * 64 + q;
    if (j > i && j < 1000) {
      double by1 = bx[j * 4 + 0], bx1 = bx[j * 4 + 1], by2 = bx[j * 4 + 2], bx2 = bx[j * 4 + 3];
      double aj = (by2 - by1) * (bx2 - bx1);
      double iy1 = fmax(y1, by1), ix1 = fmax(x1, bx1);
      double iy2 = fmin(y2, by2), ix2 = fmin(x2, bx2);
      double inter = fmax(iy2 - iy1, 0.0) * fmax(ix2 - ix1, 0.0);
      double iou = inter / (ai + aj - inter + 1e-8);
      if (iou > 0.7) m |= (1ull << q);
    }
  }
  supp[g] = m;
}

// ---------------- greedy NMS reduce + slot scatter --------------------------
__global__ __launch_bounds__(64) void nms_reduce_d(
    const double* __restrict__ ss, const double* __restrict__ sb,
    const unsigned long long* __restrict__ supp,
    float* __restrict__ rois, double* __restrict__ rois64) {
  __shared__ unsigned long long aliveS[16];
  __shared__ int pref[16];
  const int b = blockIdx.x, lane = threadIdx.x;
  unsigned long long myword = 0;
  if (lane < 16) {
    for (int q = 0; q < 64; ++q) {
      int j = lane * 64 + q;
      if (j < 1000 && ss[b * 1000 + j] > 0.0) myword |= (1ull << q);
    }
  }
  for (int i = 0; i < 1000; ++i) {
    unsigned long long wv = __shfl(myword, i >> 6);
    if ((wv >> (i & 63)) & 1ull) {
      if (lane < 16) myword &= ~supp[(size_t)b * 16000 + i * 16 + lane];
    }
  }
  if (lane < 16) aliveS[lane] = myword;
  __syncthreads();
  if (lane == 0) {
    int s = 0;
    for (int w = 0; w < 16; ++w) { pref[w] = s; s += __popcll(aliveS[w]); }
  }
  float* ro = rois + b * 4000;
  double* rd = rois64 + b * 4000;
  for (int k = lane; k < 4000; k += 64) { ro[k] = 0.0f; rd[k] = 0.0; }
  __syncthreads();
  for (int j = lane; j < 1000; j += 64) {
    int w = j >> 6;
    unsigned long long word = aliveS[w];
    if ((word >> (j & 63)) & 1ull) {
      unsigned long long below = (j & 63) ? (word & ((1ull << (j & 63)) - 1ull)) : 0ull;
      int slot = pref[w] + __popcll(below);
      const double* bp = sb + (b * 1000 + j) * 4;
      ro[slot * 4 + 0] = (float)bp[0]; ro[slot * 4 + 1] = (float)bp[1];
      ro[slot * 4 + 2] = (float)bp[2]; ro[slot * 4 + 3] = (float)bp[3];
      rd[slot * 4 + 0] = bp[0]; rd[slot * 4 + 1] = bp[1];
      rd[slot * 4 + 2] = bp[2]; rd[slot * 4 + 3] = bp[3];
    }
  }
}

// ---------------- ROI align: f64 sampling -> hi/lo bf16 feats ---------------
__global__ __launch_bounds__(256) void roi_align_d(
    const double* __restrict__ o2, const double* __restrict__ o3,
    const double* __restrict__ o4, const double* __restrict__ o5,
    const double* __restrict__ o6, const double* __restrict__ rois64,
    unsigned short* __restrict__ featsH, unsigned short* __restrict__ featsL) {
  __shared__ double s_wy[14], s_wx[14];
  __shared__ int s_y0[14], s_y1[14], s_x0[14], s_x1[14];
  const int t = threadIdx.x;
  const int b = blockIdx.x / 1000, r = blockIdx.x % 1000;
  const double* box = rois64 + (b * 1000 + r) * 4;
  double b0 = box[0], b1 = box[1], b2 = box[2], b3 = box[3];
  double h = b2 - b0, w = b3 - b1;
  double size = sqrt(fmax(h * w, 1e-8));
  double lf = floor(log2(size / 224.0) + 4.0);
  lf = fmin(fmax(lf, 2.0), 6.0);
  int lvl = (int)lf;
  int stride_i = 1 << lvl;
  double stride = (double)stride_i;
  int fs_i = 512 >> lvl;
  double fs = (double)fs_i;
  if (t < 14) {
    double v = b0 / stride + ((t + 0.5) * (h / stride)) / 14.0 - 0.5;
    v = fmin(fmax(v, 0.0), fs - 1.0);
    int i0 = (int)floor(v);
    s_y0[t] = i0; s_y1[t] = min(i0 + 1, fs_i - 1); s_wy[t] = v - (double)i0;
  } else if (t >= 64 && t < 78) {
    int u = t - 64;
    double v = b1 / stride + ((u + 0.5) * (w / stride)) / 14.0 - 0.5;
    v = fmin(fmax(v, 0.0), fs - 1.0);
    int i0 = (int)floor(v);
    s_x0[u] = i0; s_x1[u] = min(i0 + 1, fs_i - 1); s_wx[u] = v - (double)i0;
  }
  __syncthreads();
  const double* omaps[5] = {o2, o3, o4, o5, o6};
  const double* fm = omaps[lvl - 2] + (size_t)b * fs_i * fs_i * 256 + t;
  size_t obase = ((size_t)(b * 1000 + r) * 49) * 256 + t;
  for (int oy = 0; oy < 7; ++oy) {
    double acc[7] = {0, 0, 0, 0, 0, 0, 0};
#pragma unroll
    for (int sy = 0; sy < 2; ++sy) {
      int yy = oy * 2 + sy;
      int y0 = s_y0[yy], y1 = s_y1[yy];
      double wy = s_wy[yy];
      const double* r0 = fm + (size_t)y0 * fs_i * 256;
      const double* r1 = fm + (size_t)y1 * fs_i * 256;
      for (int ox = 0; ox < 7; ++ox) {
#pragma unroll
        for (int sx = 0; sx < 2; ++sx) {
          int xx = ox * 2 + sx;
          int x0 = s_x0[xx], x1 = s_x1[xx];
          double wx = s_wx[xx];
          double v00 = r0[x0 * 256], v01 = r0[x1 * 256];
          double v10 = r1[x0 * 256], v11 = r1[x1 * 256];
          double val = (1.0 - wy) * ((1.0 - wx) * v00 + wx * v01) +
                       wy * ((1.0 - wx) * v10 + wx * v11);
          acc[ox] += val;
        }
      }
    }
    for (int ox = 0; ox < 7; ++ox) {
      float v = (float)(acc[ox] * 0.25);
      unsigned short hh = f2bf(v);
      size_t idx = obase + (size_t)(oy * 7 + ox) * 256;
      featsH[idx] = hh;
      featsL[idx] = f2bf(v - bf2f(hh));
    }
  }
}

// ---------------- split f32 [K][N] -> bf16 hi/lo transposed [N][K] ----------
__global__ __launch_bounds__(256) void split_transpose(
    const float* __restrict__ W, unsigned short* __restrict__ TH,
    unsigned short* __restrict__ TL, int K, int N) {
  __shared__ unsigned short shh[32 * 33], shl[32 * 33];
  const int kt = blockIdx.y * 32, nt = blockIdx.x * 32;
  const int tx = threadIdx.x & 31, ty = threadIdx.x >> 5;   // 32x8
  for (int yy = ty; yy < 32; yy += 8) {
    float v = W[(size_t)(kt + yy) * N + nt + tx];
    unsigned short h = f2bf(v);
    shh[yy * 33 + tx] = h;
    shl[yy * 33 + tx] = f2bf(v - bf2f(h));
  }
  __syncthreads();
  for (int yy = ty; yy < 32; yy += 8) {
    TH[(size_t)(nt + yy) * K + kt + tx] = shh[tx * 33 + yy];
    TL[(size_t)(nt + yy) * K + kt + tx] = shl[tx * 33 + yy];
  }
}

// ---------------- split f32 rows -> bf16 hi/lo (no transpose) ---------------
__global__ void split_rows(const float* __restrict__ X, unsigned short* __restrict__ H,
                           unsigned short* __restrict__ L, int n) {
  int i = blockIdx.x * 256 + threadIdx.x;
  if (i < n) {
    float v = X[i];
    unsigned short h = f2bf(v);
    H[i] = h;
    L[i] = f2bf(v - bf2f(h));
  }
}

// ---------------- split-bf16 MFMA GEMM 128x128: C = relu?(A@B + bias) -------
// A (hi/lo) [M][K] bf16, BT (hi/lo) [N][K] bf16. Tile 128x128, BK=32.
// 4 waves: wave w -> n-half (w&1, 64 cols), m-half (w>>1, 64 rows); per wave
// 4x4 tiles of 16x16, 3 mfma each (aL*bH + aH*bL + aH*bH) — same per-output
// accumulation sequence as R4 (bitwise identical).
template <bool RELU>
__global__ __launch_bounds__(256) void gemm_mfma_split(
    const unsigned short* __restrict__ AH, const unsigned short* __restrict__ AL,
    const unsigned short* __restrict__ BTH, const unsigned short* __restrict__ BTL,
    const float* __restrict__ bias, float* __restrict__ C, int M, int N, int K) {
  __shared__ __align__(16) unsigned short AsH[128 * 40], AsL[128 * 40];
  __shared__ __align__(16) unsigned short BsH[128 * 40], BsL[128 * 40];
  const int t = threadIdx.x;
  const int lane = t & 63;
  const int wave = t >> 6;
  const int lm = lane & 15, lq = lane >> 4;
  const int wn = wave & 1, wm = wave >> 1;
  const int m0 = blockIdx.y * 128, n0 = blockIdx.x * 128;
  const int sr = t >> 1;            // 0..127
  const int sk = (t & 1) * 16;      // 0,16

  f4_t acc[4][4];
#pragma unroll
  for (int mt = 0; mt < 4; ++mt)
#pragma unroll
    for (int nt = 0; nt < 4; ++nt) acc[mt][nt] = (f4_t){0.f, 0.f, 0.f, 0.f};

  const uint4 zz = {0u, 0u, 0u, 0u};
  for (int k0 = 0; k0 < K; k0 += 32) {
    __syncthreads();
    // stage A 128x32 (hi/lo): thread -> row sr, k-halves sk..sk+15
    {
      uint4 vh0 = zz, vh1 = zz, vl0 = zz, vl1 = zz;
      if (m0 + sr < M) {
        size_t off = (size_t)(m0 + sr) * K + k0 + sk;
        vh0 = *(const uint4*)&AH[off];
        vh1 = *(const uint4*)&AH[off + 8];
        vl0 = *(const uint4*)&AL[off];
        vl1 = *(const uint4*)&AL[off + 8];
      }
      *(uint4*)&AsH[sr * 40 + sk] = vh0;
      *(uint4*)&AsH[sr * 40 + sk + 8] = vh1;
      *(uint4*)&AsL[sr * 40 + sk] = vl0;
      *(uint4*)&AsL[sr * 40 + sk + 8] = vl1;
    }
    // stage B 128x32 (hi/lo), rows n0..n0+127 of BT
    {
      size_t off = (size_t)(n0 + sr) * K + k0 + sk;
      *(uint4*)&BsH[sr * 40 + sk] = *(const uint4*)&BTH[off];
      *(uint4*)&BsH[sr * 40 + sk + 8] = *(const uint4*)&BTH[off + 8];
      *(uint4*)&BsL[sr * 40 + sk] = *(const uint4*)&BTL[off];
      *(uint4*)&BsL[sr * 40 + sk + 8] = *(const uint4*)&BTL[off + 8];
    }
    __syncthreads();

    bf8_t aH[4], aL[4], bH[4], bL[4];
#pragma unroll
    for (int mt = 0; mt < 4; ++mt) {
      int idx = (wm * 64 + mt * 16 + lm) * 40 + lq * 8;
      aH[mt] = *(const bf8_t*)&AsH[idx];
      aL[mt] = *(const bf8_t*)&AsL[idx];
    }
#pragma unroll
    for (int nt = 0; nt < 4; ++nt) {
      int idx = (wn * 64 + nt * 16 + lm) * 40 + lq * 8;
      bH[nt] = *(const bf8_t*)&BsH[idx];
      bL[nt] = *(const bf8_t*)&BsL[idx];
    }
#pragma unroll
    for (int mt = 0; mt < 4; ++mt)
#pragma unroll
      for (int nt = 0; nt < 4; ++nt) {
        f4_t a0 = acc[mt][nt];
        a0 = __builtin_amdgcn_mfma_f32_16x16x32_bf16(aL[mt], bH[nt], a0, 0, 0, 0);
        a0 = __builtin_amdgcn_mfma_f32_16x16x32_bf16(aH[mt], bL[nt], a0, 0, 0, 0);
        a0 = __builtin_amdgcn_mfma_f32_16x16x32_bf16(aH[mt], bH[nt], a0, 0, 0, 0);
        acc[mt][nt] = a0;
      }
  }
  // D layout (verified 16x16): col = lane&15, row = (lane>>4)*4 + reg
#pragma unroll
  for (int mt = 0; mt < 4; ++mt) {
#pragma unroll
    for (int nt = 0; nt < 4; ++nt) {
      int ncol = n0 + wn * 64 + nt * 16 + lm;
      float bb = bias[ncol];
#pragma unroll
      for (int r = 0; r < 4; ++r) {
        int m = m0 + wm * 64 + mt * 16 + lq * 4 + r;
        if (m < M) {
          float v = acc[mt][nt][r] + bb;
          if (RELU) v = fmaxf(v, 0.0f);
          C[(size_t)m * N + ncol] = v;
        }
      }
    }
  }
}

// ---------------- final box(4) + cls(81) heads, f32 -------------------------
__global__ __launch_bounds__(128) void boxcls_kernel(
    const float* __restrict__ x, const float* __restrict__ w_box,
    const float* __restrict__ b_box, const float* __restrict__ w_cls,
    const float* __restrict__ b_cls, float* __restrict__ out) {
  __shared__ float xv[1024];
  const int t = threadIdx.x;
  const int row = blockIdx.x;
  const float* xp = x + (size_t)row * 1024;
#pragma unroll
  for (int k = 0; k < 8; ++k) xv[k * 128 + t] = xp[k * 128 + t];
  __syncthreads();
  if (t < 4) {
    float acc = b_box[t];
    for (int k = 0; k < 1024; ++k) acc += xv[k] * w_box[k * 4 + t];
    out[8000 + row * 4 + t] = acc;
  } else if (t < 85) {
    int j = t - 4;
    float acc = b_cls[j];
    for (int k = 0; k < 1024; ++k) acc += xv[k] * w_cls[k * 81 + j];
    out[16000 + row * 81 + j] = acc;
  }
}

// ---------------------------------------------------------------------------
extern "C" void kernel_launch(void* const* d_in, const int* in_sizes, int n_in,
                              void* d_out, int out_size, void* d_ws, size_t ws_size,
                              hipStream_t stream) {
  (void)in_sizes; (void)n_in; (void)out_size; (void)ws_size;

  const float* c_in[4] = {(const float*)d_in[0], (const float*)d_in[1],
                          (const float*)d_in[2], (const float*)d_in[3]};
  const float *w_l[5], *b_l[5], *w_o[5], *b_o[5];
  for (int l = 0; l < 5; ++l) {
    w_l[l] = (const float*)d_in[4 + l * 4 + 0];
    b_l[l] = (const float*)d_in[4 + l * 4 + 1];
    w_o[l] = (const float*)d_in[4 + l * 4 + 2];
    b_o[l] = (const float*)d_in[4 + l * 4 + 3];
  }
  const float* w_rpn = (const float*)d_in[24];
  const float* b_rpn = (const float*)d_in[25];
  const float* w_obj = (const float*)d_in[26];
  const float* b_obj = (const float*)d_in[27];
  const float* w_dlt = (const float*)d_in[28];
  const float* b_dlt = (const float*)d_in[29];
  const float* w_fc1 = (const float*)d_in[30];
  const float* b_fc1 = (const float*)d_in[31];
  const float* w_fc2 = (const float*)d_in[32];
  const float* b_fc2 = (const float*)d_in[33];
  const float* w_box = (const float*)d_in[34];
  const float* b_box = (const float*)d_in[35];
  const float* w_cls = (const float*)d_in[36];
  const float* b_cls = (const float*)d_in[37];

  char* W8 = (char*)d_ws;
  double* o64 = (double*)(W8 + 0);
  double* p64 = (double*)(W8 + 89391104);
  float* c6buf = (float*)(W8 + 178782208);
  double* scores = (double*)(W8 + 179830784);
  double* boxes = (double*)(W8 + 182973440);
  double* ssb = (double*)(W8 + 195544064);
  double* sbb = (double*)(W8 + 195560064);
  double* rois64 = (double*)(W8 + 195624064);
  unsigned long long* suppb = (unsigned long long*)(W8 + 195688064);
  unsigned short* featsH = (unsigned short*)(W8 + 89391104);
  unsigned short* featsL = (unsigned short*)(W8 + 139567104);
  float* fc1b = (float*)(W8 + 0);
  float* fc2b = (float*)(W8 + 8192000);
  unsigned short* wT1H = (unsigned short*)(W8 + 16384000);
  unsigned short* wT1L = (unsigned short*)(W8 + 42074112);
  unsigned short* wT2H = (unsigned short*)(W8 + 67764224);
  unsigned short* wT2L = (unsigned short*)(W8 + 69861376);
  unsigned short* fc1H = (unsigned short*)(W8 + 71958528);
  unsigned short* fc1L = (unsigned short*)(W8 + 76054528);
  float* outf = (float*)d_out;

  const size_t OFF[5] = {0, 8388608, 10485760, 11010048, 11141120};
  double* o[5]; double* p[5];
  for (int l = 0; l < 5; ++l) { o[l] = o64 + OFF[l]; p[l] = p64 + OFF[l]; }

  const int HS[5] = {128, 64, 32, 16, 8};
  const int a_off[5] = {0, 147456, 184320, 193536, 195840};
  const double strides[5] = {4.0, 8.0, 16.0, 32.0, 64.0};
  const double SZ[5] = {16.0, 32.0, 64.0, 128.0, 256.0};
  AnchorHW anc[5];
  for (int l = 0; l < 5; ++l) {
    const double ars[3] = {0.5, 1.0, 2.0};
    for (int s = 0; s < 3; ++s) {
      double sc = pow(2.0, s / 3.0);
      for (int a = 0; a < 3; ++a) {
        double sq = sqrt(ars[a]);
        anc[l].hh[s * 3 + a] = SZ[l] * sc / sq;
        anc[l].ww[s * 3 + a] = SZ[l] * sc * sq;
      }
    }
  }

  // ---- FPN (f64) ----
  maxpool_kernel<<<1024, 256, 0, stream>>>(c_in[3], c6buf);
  lateral_d<2048><<<32, 256, 0, stream>>>(c6buf, w_l[4], b_l[4], p[4]);      // p6
  lateral_d<2048><<<128, 256, 0, stream>>>(c_in[3], w_l[3], b_l[3], p[3]);   // p5
  upadd_d<<<512, 256, 0, stream>>>(p[3], p[4], 16, 16);
  lateral_d<1024><<<512, 256, 0, stream>>>(c_in[2], w_l[2], b_l[2], p[2]);   // p4
  upadd_d<<<2048, 256, 0, stream>>>(p[2], p[3], 32, 32);
  lateral_d<512><<<2048, 256, 0, stream>>>(c_in[1], w_l[1], b_l[1], p[1]);   // p3
  upadd_d<<<8192, 256, 0, stream>>>(p[1], p[2], 64, 64);
  lateral_d<256><<<8192, 256, 0, stream>>>(c_in[0], w_l[0], b_l[0], p[0]);   // p2
  upadd_d<<<32768, 256, 0, stream>>>(p[0], p[1], 128, 128);

  // ---- fused 5-level conv passes ----
  Conv5Args co, ct;
  int total = 0;
  for (int l = 0; l < 5; ++l) {
    int nbx = (HS[l] + 15) / 16;
    co.in[l] = p[l]; co.out[l] = o[l]; co.w[l] = w_o[l]; co.b[l] = b_o[l];
    ct.in[l] = o[l]; ct.out[l] = p[l]; ct.w[l] = w_rpn;  ct.b[l] = b_rpn;
    co.H[l] = ct.H[l] = HS[l];
    co.nbx[l] = ct.nbx[l] = nbx;
    co.off[l] = ct.off[l] = total;
    total += nbx * HS[l] * 2;
  }
  co.off[5] = ct.off[5] = total;   // 2736
  conv3x3_fused<false><<<total, 256, 0, stream>>>(co);
  conv3x3_fused<true><<<total, 256, 0, stream>>>(ct);

  for (int l = 0; l < 5; ++l) {
    dim3 g(HS[l], HS[l], 2);
    rpn_head_d<<<g, 64, 0, stream>>>(p[l], w_obj, b_obj, w_dlt, b_dlt, scores, boxes,
                                     HS[l], HS[l], a_off[l], strides[l], anc[l]);
  }
  // ---- top-1000 + NMS (f64) ----
  topk_d<<<2, 1024, 0, stream>>>(scores, boxes, ssb, sbb);
  suppmat_d<<<125, 256, 0, stream>>>(sbb, suppb);
  nms_reduce_d<<<2, 64, 0, stream>>>(ssb, sbb, suppb, outf, rois64);
  // ---- ROI align (emits hi/lo bf16 feats) ----
  roi_align_d<<<2000, 256, 0, stream>>>(o[0], o[1], o[2], o[3], o[4], rois64,
                                        featsH, featsL);
  // ---- FC head: split weights (o64 now dead), then MFMA GEMMs ----
  split_transpose<<<dim3(32, 392), 256, 0, stream>>>(w_fc1, wT1H, wT1L, 12544, 1024);
  split_transpose<<<dim3(32, 32), 256, 0, stream>>>(w_fc2, wT2H, wT2L, 1024, 1024);
  gemm_mfma_split<true><<<dim3(8, 16), 256, 0, stream>>>(
      featsH, featsL, wT1H, wT1L, b_fc1, fc1b, 2000, 1024, 12544);
  split_rows<<<8000, 256, 0, stream>>>(fc1b, fc1H, fc1L, 2048000);
  gemm_mfma_split<true><<<dim3(8, 16), 256, 0, stream>>>(
      fc1H, fc1L, wT2H, wT2L, b_fc2, fc2b, 2000, 1024, 1024);
  boxcls_kernel<<<2000, 128, 0, stream>>>(fc2b, w_box, b_box, w_cls, b_cls, outf);
}